// Round 4
// baseline (368.926 us; speedup 1.0000x reference)
//
#include <hip/hip_runtime.h>
#include <math.h>

#define TT 2048
#define TD 256
#define BN 2048
#define BT 32768
#define KTOP 100
#define NB 64        // histogram bins over [-1,1]
#define CAP 512      // per-row boundary-bin list capacity
#define BROWS 256    // rows per block (4 waves x 4 tiles x 16)
#define SLICE 512    // cols per block
#define NSLICE 64    // BT / SLICE
#define NCHUNK 8     // SLICE / 64

typedef __attribute__((ext_vector_type(8))) short short8v;
typedef __attribute__((ext_vector_type(4))) float float4v;

__device__ __forceinline__ unsigned short f2bf(float f) {
    unsigned u = __float_as_uint(f);
    u += 0x7fffu + ((u >> 16) & 1u);   // round-to-nearest-even
    return (unsigned short)(u >> 16);
}

// ushort offset of (row_or_col, d0 = 4*lane) in the MFMA-fragment-tiled layout
// [blk16][ks(8)][g(4)][c(16)][8 elems]
__device__ __forceinline__ int tile_off_us(int col, int l) {
    int ks = l >> 3;
    int g = (l >> 1) & 3;
    int e = (l & 1) * 4;
    return ((((col >> 4) * 8 + ks) * 4 + g) * 16 + (col & 15)) * 8 + e;
}

__device__ __forceinline__ void gload16(const void* g, void* l) {
    __builtin_amdgcn_global_load_lds(
        (const __attribute__((address_space(1))) unsigned*)g,
        (__attribute__((address_space(3))) unsigned*)l, 16, 0, 0);
}

// ---------------------------------------------------------------------------
__global__ __launch_bounds__(256) void kzero(unsigned* __restrict__ hist,
                                             int* __restrict__ cnt) {
    int i = blockIdx.x * 256 + threadIdx.x;   // grid covers BN*NB exactly
    hist[i] = 0u;
    if (i < BN) cnt[i] = 0;
}

// normalize negatives -> bf16 fragment-tiled layout. 1 wave per col.
__global__ __launch_bounds__(256) void kprep(const float* __restrict__ tgt,
                                             unsigned short* __restrict__ negT) {
    const int col = blockIdx.x * 4 + (threadIdx.x >> 6);
    const int lane = threadIdx.x & 63;
    float4 v = *reinterpret_cast<const float4*>(tgt + (size_t)col * TD + lane * 4);
    float s = v.x * v.x + v.y * v.y + v.z * v.z + v.w * v.w;
    for (int off = 32; off > 0; off >>= 1) s += __shfl_down(s, off, 64);
    s = __shfl(s, 0, 64);
    const float inv = 1.0f / sqrtf(s);
    ushort4 o;
    o.x = f2bf(v.x * inv); o.y = f2bf(v.y * inv);
    o.z = f2bf(v.z * inv); o.w = f2bf(v.w * inv);
    *reinterpret_cast<ushort4*>(negT + tile_off_us(col, lane)) = o;
}

// per anchor row: normalized anchor (bf16, tiled), acos*10 numerator, phone.
__global__ __launch_bounds__(64) void kanchor(const float* __restrict__ ctx,
                                              const float* __restrict__ tgt,
                                              const int* __restrict__ mask_index,
                                              const int* __restrict__ phone,
                                              unsigned short* __restrict__ ancT,
                                              float* __restrict__ acosP,
                                              int* __restrict__ phoneA) {
    const int r = blockIdx.x;
    const int b = r >> 7;
    const int n = r & 127;
    const int t = mask_index[n];
    const int lane = threadIdx.x;
    const size_t base = ((size_t)b * TT + t) * TD;
    float4 a = *reinterpret_cast<const float4*>(ctx + base + lane * 4);
    float4 p = *reinterpret_cast<const float4*>(tgt + base + lane * 4);
    float sa = a.x * a.x + a.y * a.y + a.z * a.z + a.w * a.w;
    float sp = p.x * p.x + p.y * p.y + p.z * p.z + p.w * p.w;
    float dp = a.x * p.x + a.y * p.y + a.z * p.z + a.w * p.w;
    for (int off = 32; off > 0; off >>= 1) {
        sa += __shfl_down(sa, off, 64);
        sp += __shfl_down(sp, off, 64);
        dp += __shfl_down(dp, off, 64);
    }
    sa = __shfl(sa, 0, 64);
    sp = __shfl(sp, 0, 64);
    dp = __shfl(dp, 0, 64);
    const float an = sqrtf(sa);
    const float inva = 1.0f / an;
    if (lane == 0) {
        float cp = dp / (an * sqrtf(sp));
        cp = fminf(1.f, fmaxf(-1.f, cp));
        acosP[r] = acosf(cp) * 10.0f;
        phoneA[r] = phone[b * TT + t];
    }
    ushort4 o;
    o.x = f2bf(a.x * inva); o.y = f2bf(a.y * inva);
    o.z = f2bf(a.z * inva); o.w = f2bf(a.w * inva);
    *reinterpret_cast<ushort4*>(ancT + tile_off_us(r, lane)) = o;
}

// ---------------------------------------------------------------------------
// pass 1: 256 rows x 512 cols per block. LDS-staged B chunks (global_load_lds),
// 4 waves x mt=4 row-tiles reuse each chunk. Packed LDS histogram.
// ---------------------------------------------------------------------------
__global__ __launch_bounds__(256, 2) void kpass1(const short8v* __restrict__ ancT8,
                                                 const char* __restrict__ negTc,
                                                 const int* __restrict__ phoneT,
                                                 const int* __restrict__ phoneA,
                                                 unsigned* __restrict__ hist) {
    __shared__ short8v bufB[2048];            // 32 KB: one 64-col chunk
    __shared__ unsigned histp[BROWS * 33];    // 2 bins/u32, +1 pad per row
    __shared__ int phS[SLICE];
    const int tid = threadIdx.x;
    const int w = tid >> 6;
    const int lane = tid & 63;
    const int g = lane >> 4;
    const int c = lane & 15;
    const int rt = blockIdx.x >> 6;           // 0..7
    const int ct = blockIdx.x & 63;           // 0..63
    const int row0 = rt * BROWS;
    const int colbase = ct * SLICE;

    for (int i = tid; i < BROWS * 33; i += 256) histp[i] = 0u;
    if (tid < SLICE / 4)
        *reinterpret_cast<int4*>(&phS[tid * 4]) =
            *reinterpret_cast<const int4*>(phoneT + colbase + tid * 4);

    short8v af[4][8];
#pragma unroll
    for (int mt = 0; mt < 4; ++mt) {
        const int tile = rt * 16 + w * 4 + mt;
#pragma unroll
        for (int ks = 0; ks < 8; ++ks)
            af[mt][ks] = ancT8[(tile * 8 + ks) * 64 + lane];
    }
    int phA_r[4][4];
#pragma unroll
    for (int mt = 0; mt < 4; ++mt)
#pragma unroll
        for (int j = 0; j < 4; ++j)
            phA_r[mt][j] = phoneA[row0 + w * 64 + mt * 16 + g * 4 + j];

    for (int chunk = 0; chunk < NCHUNK; ++chunk) {
        const int cb = colbase + chunk * 64;
        const char* gsrc = negTc + (size_t)(cb >> 4) * 8192;
#pragma unroll
        for (int i = 0; i < 8; ++i)
            gload16(gsrc + i * 4096 + tid * 16, (char*)bufB + i * 4096 + tid * 16);
        __syncthreads();   // stage complete (drains vmcnt) + prologue LDS visible

        float4v acc[4][4];
#pragma unroll
        for (int mt = 0; mt < 4; ++mt)
#pragma unroll
            for (int nt = 0; nt < 4; ++nt)
                acc[mt][nt] = (float4v){0.f, 0.f, 0.f, 0.f};
        __builtin_amdgcn_s_setprio(1);
#pragma unroll
        for (int nt = 0; nt < 4; ++nt) {
#pragma unroll
            for (int ks = 0; ks < 8; ++ks) {
                short8v bf = bufB[(nt * 8 + ks) * 64 + lane];
                acc[0][nt] = __builtin_amdgcn_mfma_f32_16x16x32_bf16(af[0][ks], bf, acc[0][nt], 0, 0, 0);
                acc[1][nt] = __builtin_amdgcn_mfma_f32_16x16x32_bf16(af[1][ks], bf, acc[1][nt], 0, 0, 0);
                acc[2][nt] = __builtin_amdgcn_mfma_f32_16x16x32_bf16(af[2][ks], bf, acc[2][nt], 0, 0, 0);
                acc[3][nt] = __builtin_amdgcn_mfma_f32_16x16x32_bf16(af[3][ks], bf, acc[3][nt], 0, 0, 0);
            }
        }
        __builtin_amdgcn_s_setprio(0);

#pragma unroll
        for (int nt = 0; nt < 4; ++nt) {
            const int ph = phS[chunk * 64 + nt * 16 + c];
#pragma unroll
            for (int mt = 0; mt < 4; ++mt) {
#pragma unroll
                for (int j = 0; j < 4; ++j) {
                    if (ph != phA_r[mt][j]) {
                        float v = fminf(1.f, fmaxf(-1.f, acc[mt][nt][j]));
                        int bb = (int)((v + 1.0f) * 32.0f);
                        bb = bb > NB - 1 ? NB - 1 : bb;
                        const int lrow = w * 64 + mt * 16 + g * 4 + j;
                        atomicAdd(&histp[lrow * 33 + (bb >> 1)], 1u << ((bb & 1) * 16));
                    }
                }
            }
        }
        __syncthreads();   // protect bufB reuse
    }

    for (int i = tid; i < BROWS * 32; i += 256) {
        int r = i >> 5, pb = i & 31;
        unsigned u = histp[r * 33 + pb];
        if (u & 0xffffu) atomicAdd(&hist[(size_t)(row0 + r) * NB + pb * 2], u & 0xffffu);
        if (u >> 16)     atomicAdd(&hist[(size_t)(row0 + r) * NB + pb * 2 + 1], u >> 16);
    }
}

// find the k-th-value bin per row
__global__ __launch_bounds__(256) void kbstar(const unsigned* __restrict__ hist,
                                              int* __restrict__ bstar,
                                              int* __restrict__ rneedA) {
    const int row = blockIdx.x * 256 + threadIdx.x;
    const unsigned* h = hist + (size_t)row * NB;
    unsigned tot = 0;
    for (int i = 0; i < NB; ++i) tot += h[i];
    int kp = (int)tot < KTOP ? (int)tot : KTOP;
    if (kp == 0) { bstar[row] = -1; rneedA[row] = 0; return; }
    unsigned cum = 0;
    int b = 0;
    for (; b < NB; ++b) {
        if (cum + h[b] >= (unsigned)kp) break;
        cum += h[b];
    }
    bstar[row] = b;
    rneedA[row] = kp - (int)cum;
}

// ---------------------------------------------------------------------------
// pass 2: same GEMM (bit-identical), sum exp(acos*10) for bins < bstar,
// append boundary-bin values to per-row global lists.
// ---------------------------------------------------------------------------
__global__ __launch_bounds__(256, 2) void kpass2(const short8v* __restrict__ ancT8,
                                                 const char* __restrict__ negTc,
                                                 const int* __restrict__ phoneT,
                                                 const int* __restrict__ phoneA,
                                                 const int* __restrict__ bstar,
                                                 float* __restrict__ partials,
                                                 float* __restrict__ list,
                                                 int* __restrict__ cnt) {
    __shared__ short8v bufB[2048];
    __shared__ int phS[SLICE];
    const int tid = threadIdx.x;
    const int w = tid >> 6;
    const int lane = tid & 63;
    const int g = lane >> 4;
    const int c = lane & 15;
    const int rt = blockIdx.x >> 6;
    const int ct = blockIdx.x & 63;
    const int row0 = rt * BROWS;
    const int colbase = ct * SLICE;

    if (tid < SLICE / 4)
        *reinterpret_cast<int4*>(&phS[tid * 4]) =
            *reinterpret_cast<const int4*>(phoneT + colbase + tid * 4);

    short8v af[4][8];
#pragma unroll
    for (int mt = 0; mt < 4; ++mt) {
        const int tile = rt * 16 + w * 4 + mt;
#pragma unroll
        for (int ks = 0; ks < 8; ++ks)
            af[mt][ks] = ancT8[(tile * 8 + ks) * 64 + lane];
    }
    // packed per-row scalars: phone (low16) | bstar<<16 (arith-shift unpack)
    int pb_r[4][4];
#pragma unroll
    for (int mt = 0; mt < 4; ++mt)
#pragma unroll
        for (int j = 0; j < 4; ++j) {
            const int gr = row0 + w * 64 + mt * 16 + g * 4 + j;
            pb_r[mt][j] = (phoneA[gr] & 0xffff) | (bstar[gr] << 16);
        }

    float lsum[4][4];
#pragma unroll
    for (int mt = 0; mt < 4; ++mt)
#pragma unroll
        for (int j = 0; j < 4; ++j) lsum[mt][j] = 0.f;

    for (int chunk = 0; chunk < NCHUNK; ++chunk) {
        const int cb = colbase + chunk * 64;
        const char* gsrc = negTc + (size_t)(cb >> 4) * 8192;
#pragma unroll
        for (int i = 0; i < 8; ++i)
            gload16(gsrc + i * 4096 + tid * 16, (char*)bufB + i * 4096 + tid * 16);
        __syncthreads();

        float4v acc[4][4];
#pragma unroll
        for (int mt = 0; mt < 4; ++mt)
#pragma unroll
            for (int nt = 0; nt < 4; ++nt)
                acc[mt][nt] = (float4v){0.f, 0.f, 0.f, 0.f};
        __builtin_amdgcn_s_setprio(1);
#pragma unroll
        for (int nt = 0; nt < 4; ++nt) {
#pragma unroll
            for (int ks = 0; ks < 8; ++ks) {
                short8v bf = bufB[(nt * 8 + ks) * 64 + lane];
                acc[0][nt] = __builtin_amdgcn_mfma_f32_16x16x32_bf16(af[0][ks], bf, acc[0][nt], 0, 0, 0);
                acc[1][nt] = __builtin_amdgcn_mfma_f32_16x16x32_bf16(af[1][ks], bf, acc[1][nt], 0, 0, 0);
                acc[2][nt] = __builtin_amdgcn_mfma_f32_16x16x32_bf16(af[2][ks], bf, acc[2][nt], 0, 0, 0);
                acc[3][nt] = __builtin_amdgcn_mfma_f32_16x16x32_bf16(af[3][ks], bf, acc[3][nt], 0, 0, 0);
            }
        }
        __builtin_amdgcn_s_setprio(0);

#pragma unroll
        for (int nt = 0; nt < 4; ++nt) {
            const int ph = phS[chunk * 64 + nt * 16 + c];
#pragma unroll
            for (int mt = 0; mt < 4; ++mt) {
#pragma unroll
                for (int j = 0; j < 4; ++j) {
                    const int pb = pb_r[mt][j];
                    if (ph != (pb & 0xffff)) {
                        float v = fminf(1.f, fmaxf(-1.f, acc[mt][nt][j]));
                        int bb = (int)((v + 1.0f) * 32.0f);
                        bb = bb > NB - 1 ? NB - 1 : bb;
                        const int bs = pb >> 16;
                        if (bb < bs) {
                            lsum[mt][j] += expf(acosf(v) * 10.0f);
                        } else if (bb == bs) {
                            const int gr = row0 + w * 64 + mt * 16 + g * 4 + j;
                            int idx = atomicAdd(&cnt[gr], 1);
                            if (idx < CAP) list[(size_t)gr * CAP + idx] = v;
                        }
                    }
                }
            }
        }
        __syncthreads();
    }

    // deterministic per-row reduction across the 16 column-lanes (same g)
#pragma unroll
    for (int mt = 0; mt < 4; ++mt) {
#pragma unroll
        for (int j = 0; j < 4; ++j) {
            float s = lsum[mt][j];
            s += __shfl_xor(s, 1, 64);
            s += __shfl_xor(s, 2, 64);
            s += __shfl_xor(s, 4, 64);
            s += __shfl_xor(s, 8, 64);
            if (c == 0) {
                const int gr = row0 + w * 64 + mt * 16 + g * 4 + j;
                partials[(size_t)gr * NSLICE + ct] = s;
            }
        }
    }
}

// final per-row: sum partials (fixed order) + exact remainder extraction.
__global__ __launch_bounds__(64) void kfinal(const float* __restrict__ partials,
                                             const float* __restrict__ list,
                                             const int* __restrict__ cnt,
                                             const int* __restrict__ rneedA,
                                             const float* __restrict__ acosP,
                                             float* __restrict__ logits) {
    __shared__ float sl[CAP];
    const int row = blockIdx.x;
    const int lane = threadIdx.x;
    int lc = cnt[row];
    if (lc > CAP) lc = CAP;
    int rn = rneedA[row];
    if (rn > lc) rn = lc;

    float den = 0.f;
    for (int t = 0; t < NSLICE; ++t) den += partials[(size_t)row * NSLICE + t];

    for (int i = lane; i < lc; i += 64) sl[i] = list[(size_t)row * CAP + i];
    __syncthreads();

    for (int it = 0; it < rn; ++it) {
        float mv = 1e30f;
        int mi = -1;
        for (int i = lane; i < lc; i += 64) {
            float x = sl[i];
            if (x < mv) { mv = x; mi = i; }
        }
#pragma unroll
        for (int off = 1; off < 64; off <<= 1) {
            float ov = __shfl_xor(mv, off, 64);
            int oi = __shfl_xor(mi, off, 64);
            if (ov < mv || (ov == mv && oi >= 0 && (mi < 0 || oi < mi))) { mv = ov; mi = oi; }
        }
        den += expf(acosf(fminf(1.f, fmaxf(-1.f, mv))) * 10.0f);
        if (lane == 0 && mi >= 0) sl[mi] = 1e30f;
        __syncthreads();
    }
    if (lane == 0) logits[row] = acosP[row] - logf(den);
}

__global__ __launch_bounds__(256) void kloss(const float* __restrict__ logits,
                                             float* __restrict__ out) {
    __shared__ float red[256];
    int tid = threadIdx.x;
    float s = 0.f;
    for (int i = tid; i < BN; i += 256) s += logits[i];
    red[tid] = s;
    __syncthreads();
    for (int st = 128; st > 0; st >>= 1) {
        if (tid < st) red[tid] += red[tid + st];
        __syncthreads();
    }
    if (tid == 0) out[0] = -red[0] / (float)BN;
}

extern "C" void kernel_launch(void* const* d_in, const int* in_sizes, int n_in,
                              void* d_out, int out_size, void* d_ws, size_t ws_size,
                              hipStream_t stream) {
    (void)in_sizes; (void)n_in; (void)out_size; (void)ws_size;
    const float* ctx   = (const float*)d_in[0];
    const float* tgt   = (const float*)d_in[1];
    const int*   mask  = (const int*)d_in[2];
    const int*   phone = (const int*)d_in[3];
    float* out = (float*)d_out;

    char* p = (char*)d_ws;
    unsigned short* negT = (unsigned short*)p;            p += (size_t)BT * TD * 2;      // 16 MB
    unsigned short* ancT = (unsigned short*)p;            p += (size_t)BN * TD * 2;      // 1 MB
    float* acosP  = (float*)p;                            p += (size_t)BN * 4;
    int*   phoneA = (int*)p;                              p += (size_t)BN * 4;
    unsigned* hist = (unsigned*)p;                        p += (size_t)BN * NB * 4;      // 512 KB
    int*   bstarA = (int*)p;                              p += (size_t)BN * 4;
    int*   rneedA = (int*)p;                              p += (size_t)BN * 4;
    int*   cntA   = (int*)p;                              p += (size_t)BN * 4;
    float* partials = (float*)p;                          p += (size_t)BN * NSLICE * 4;  // 512 KB
    float* listA  = (float*)p;                            p += (size_t)BN * CAP * 4;     // 4 MB
    float* logits = (float*)p;                            p += (size_t)BN * 4;

    kzero<<<(BN * NB) / 256, 256, 0, stream>>>(hist, cntA);
    kprep<<<BT / 4, 256, 0, stream>>>(tgt, negT);
    kanchor<<<BN, 64, 0, stream>>>(ctx, tgt, mask, phone, ancT, acosP, phoneA);
    kpass1<<<8 * NSLICE, 256, 0, stream>>>((const short8v*)ancT, (const char*)negT,
                                           phone, phoneA, hist);
    kbstar<<<BN / 256, 256, 0, stream>>>(hist, bstarA, rneedA);
    kpass2<<<8 * NSLICE, 256, 0, stream>>>((const short8v*)ancT, (const char*)negT,
                                           phone, phoneA, bstarA, partials, listA, cntA);
    kfinal<<<BN, 64, 0, stream>>>(partials, listA, cntA, rneedA, acosP, logits);
    kloss<<<1, 256, 0, stream>>>(logits, out);
}

// Round 5
// 287.101 us; speedup vs baseline: 1.2850x; 1.2850x over previous
//
#include <hip/hip_runtime.h>
#include <math.h>

#define TT 2048
#define TD 256
#define BN 2048
#define BT 32768
#define KTOP 100
#define NB 64        // coarse histogram bins over [-1,1]
#define CAP 768      // per-row boundary-bin list capacity
#define BROWS 256    // rows per block (8 waves x 2 tiles x 16)
#define SLICE 1024   // cols per block
#define NSLICE 32    // BT / SLICE
#define NCHUNK 16    // SLICE / 64

typedef __attribute__((ext_vector_type(8))) short short8v;
typedef __attribute__((ext_vector_type(4))) float float4v;

__device__ __forceinline__ unsigned short f2bf(float f) {
    unsigned u = __float_as_uint(f);
    u += 0x7fffu + ((u >> 16) & 1u);   // round-to-nearest-even
    return (unsigned short)(u >> 16);
}

// ushort offset of (row_or_col, d0 = 4*lane) in the MFMA-fragment-tiled layout
// [blk16][ks(8)][g(4)][c(16)][8 elems]
__device__ __forceinline__ int tile_off_us(int col, int l) {
    int ks = l >> 3;
    int g = (l >> 1) & 3;
    int e = (l & 1) * 4;
    return ((((col >> 4) * 8 + ks) * 4 + g) * 16 + (col & 15)) * 8 + e;
}

__device__ __forceinline__ void gload16(const void* g, void* l) {
    __builtin_amdgcn_global_load_lds(
        (const __attribute__((address_space(1))) unsigned*)g,
        (__attribute__((address_space(3))) unsigned*)l, 16, 0, 0);
}

// ---------------------------------------------------------------------------
__global__ __launch_bounds__(256) void kzero(unsigned* __restrict__ hist,
                                             int* __restrict__ cnt) {
    int i = blockIdx.x * 256 + threadIdx.x;   // grid covers BN*NB exactly
    hist[i] = 0u;
    if (i < BN) cnt[i] = 0;
}

// normalize negatives -> bf16 fragment-tiled layout. 1 wave per col.
__global__ __launch_bounds__(256) void kprep(const float* __restrict__ tgt,
                                             unsigned short* __restrict__ negT) {
    const int col = blockIdx.x * 4 + (threadIdx.x >> 6);
    const int lane = threadIdx.x & 63;
    float4 v = *reinterpret_cast<const float4*>(tgt + (size_t)col * TD + lane * 4);
    float s = v.x * v.x + v.y * v.y + v.z * v.z + v.w * v.w;
    for (int off = 32; off > 0; off >>= 1) s += __shfl_down(s, off, 64);
    s = __shfl(s, 0, 64);
    const float inv = 1.0f / sqrtf(s);
    ushort4 o;
    o.x = f2bf(v.x * inv); o.y = f2bf(v.y * inv);
    o.z = f2bf(v.z * inv); o.w = f2bf(v.w * inv);
    *reinterpret_cast<ushort4*>(negT + tile_off_us(col, lane)) = o;
}

// per anchor row: normalized anchor (bf16, tiled), acos*10 numerator, phone.
__global__ __launch_bounds__(64) void kanchor(const float* __restrict__ ctx,
                                              const float* __restrict__ tgt,
                                              const int* __restrict__ mask_index,
                                              const int* __restrict__ phone,
                                              unsigned short* __restrict__ ancT,
                                              float* __restrict__ acosP,
                                              int* __restrict__ phoneA) {
    const int r = blockIdx.x;
    const int b = r >> 7;
    const int n = r & 127;
    const int t = mask_index[n];
    const int lane = threadIdx.x;
    const size_t base = ((size_t)b * TT + t) * TD;
    float4 a = *reinterpret_cast<const float4*>(ctx + base + lane * 4);
    float4 p = *reinterpret_cast<const float4*>(tgt + base + lane * 4);
    float sa = a.x * a.x + a.y * a.y + a.z * a.z + a.w * a.w;
    float sp = p.x * p.x + p.y * p.y + p.z * p.z + p.w * p.w;
    float dp = a.x * p.x + a.y * p.y + a.z * p.z + a.w * p.w;
    for (int off = 32; off > 0; off >>= 1) {
        sa += __shfl_down(sa, off, 64);
        sp += __shfl_down(sp, off, 64);
        dp += __shfl_down(dp, off, 64);
    }
    sa = __shfl(sa, 0, 64);
    sp = __shfl(sp, 0, 64);
    dp = __shfl(dp, 0, 64);
    const float an = sqrtf(sa);
    const float inva = 1.0f / an;
    if (lane == 0) {
        float cp = dp / (an * sqrtf(sp));
        cp = fminf(1.f, fmaxf(-1.f, cp));
        acosP[r] = acosf(cp) * 10.0f;
        phoneA[r] = phone[b * TT + t];
    }
    ushort4 o;
    o.x = f2bf(a.x * inva); o.y = f2bf(a.y * inva);
    o.z = f2bf(a.z * inva); o.w = f2bf(a.w * inva);
    *reinterpret_cast<ushort4*>(ancT + tile_off_us(r, lane)) = o;
}

// ---------------------------------------------------------------------------
// pass 1: 256 rows x 1024 cols per block, 8 waves, mt=2 row-tiles per wave.
// Double-buffered LDS B-chunks (64 cols = 32 KB), 2-phase pipeline.
// ---------------------------------------------------------------------------
__global__ __launch_bounds__(512, 2) void kpass1(const short8v* __restrict__ ancT8,
                                                 const char* __restrict__ negTc,
                                                 const int* __restrict__ phoneT,
                                                 const int* __restrict__ phoneA,
                                                 unsigned* __restrict__ hist) {
    __shared__ short8v bufB[2][2048];          // 2 x 32 KB
    __shared__ unsigned histp[BROWS * 33];     // 2 bins/u32, +1 pad per row
    __shared__ int phS[SLICE];
    const int tid = threadIdx.x;
    const int w = tid >> 6;
    const int lane = tid & 63;
    const int g = lane >> 4;
    const int c = lane & 15;
    const int rt = blockIdx.x >> 5;            // 0..7
    const int ct = blockIdx.x & 31;            // 0..31
    const int row0 = rt * BROWS;
    const int colbase = ct * SLICE;

    {   // stage chunk 0 early
        const char* gsrc = negTc + (size_t)colbase * 512;
#pragma unroll
        for (int i = 0; i < 4; ++i)
            gload16(gsrc + i * 8192 + tid * 16, (char*)&bufB[0][0] + i * 8192 + tid * 16);
    }
    for (int i = tid; i < BROWS * 33; i += 512) histp[i] = 0u;
    if (tid < SLICE / 4)
        *reinterpret_cast<int4*>(&phS[tid * 4]) =
            *reinterpret_cast<const int4*>(phoneT + colbase + tid * 4);

    short8v af[2][8];
#pragma unroll
    for (int mt = 0; mt < 2; ++mt) {
        const int tile = rt * 16 + w * 2 + mt;
#pragma unroll
        for (int ks = 0; ks < 8; ++ks)
            af[mt][ks] = ancT8[(tile * 8 + ks) * 64 + lane];
    }
    int phA_r[2][4];
#pragma unroll
    for (int mt = 0; mt < 2; ++mt)
#pragma unroll
        for (int j = 0; j < 4; ++j)
            phA_r[mt][j] = phoneA[row0 + w * 32 + mt * 16 + g * 4 + j];
    __syncthreads();   // drains chunk-0 stage

    for (int t = 0; t < NCHUNK; ++t) {
        const int cur = t & 1;
        if (t < NCHUNK - 1) {   // prefetch next chunk into other buffer
            const char* gsrc = negTc + (size_t)(colbase + (t + 1) * 64) * 512;
#pragma unroll
            for (int i = 0; i < 4; ++i)
                gload16(gsrc + i * 8192 + tid * 16,
                        (char*)&bufB[cur ^ 1][0] + i * 8192 + tid * 16);
        }
        float4v acc[2][4];
#pragma unroll
        for (int mt = 0; mt < 2; ++mt)
#pragma unroll
            for (int nt = 0; nt < 4; ++nt)
                acc[mt][nt] = (float4v){0.f, 0.f, 0.f, 0.f};
        __builtin_amdgcn_s_setprio(1);
#pragma unroll
        for (int nt = 0; nt < 4; ++nt) {
#pragma unroll
            for (int ks = 0; ks < 8; ++ks) {
                short8v bf = bufB[cur][(nt * 8 + ks) * 64 + lane];
                acc[0][nt] = __builtin_amdgcn_mfma_f32_16x16x32_bf16(af[0][ks], bf, acc[0][nt], 0, 0, 0);
                acc[1][nt] = __builtin_amdgcn_mfma_f32_16x16x32_bf16(af[1][ks], bf, acc[1][nt], 0, 0, 0);
            }
        }
        __builtin_amdgcn_s_setprio(0);

#pragma unroll
        for (int nt = 0; nt < 4; ++nt) {
            const int ph = phS[t * 64 + nt * 16 + c];
#pragma unroll
            for (int mt = 0; mt < 2; ++mt) {
#pragma unroll
                for (int j = 0; j < 4; ++j) {
                    if (ph != phA_r[mt][j]) {
                        float v = fminf(1.f, fmaxf(-1.f, acc[mt][nt][j]));
                        int bb = (int)((v + 1.0f) * 32.0f);
                        bb = bb > NB - 1 ? NB - 1 : bb;
                        const int lrow = w * 32 + mt * 16 + g * 4 + j;
                        atomicAdd(&histp[lrow * 33 + (bb >> 1)], 1u << ((bb & 1) * 16));
                    }
                }
            }
        }
        __syncthreads();   // buffer handoff + hist visibility
    }

    for (int i = tid; i < BROWS * 32; i += 512) {
        int r = i >> 5, pb = i & 31;
        unsigned u = histp[r * 33 + pb];
        if (u & 0xffffu) atomicAdd(&hist[(size_t)(row0 + r) * NB + pb * 2], u & 0xffffu);
        if (u >> 16)     atomicAdd(&hist[(size_t)(row0 + r) * NB + pb * 2 + 1], u >> 16);
    }
}

// find the k-th-value bin per row
__global__ __launch_bounds__(256) void kbstar(const unsigned* __restrict__ hist,
                                              int* __restrict__ bstar,
                                              int* __restrict__ rneedA) {
    const int row = blockIdx.x * 256 + threadIdx.x;
    const unsigned* h = hist + (size_t)row * NB;
    unsigned tot = 0;
    for (int i = 0; i < NB; ++i) tot += h[i];
    int kp = (int)tot < KTOP ? (int)tot : KTOP;
    if (kp == 0) { bstar[row] = -1; rneedA[row] = 0; return; }
    unsigned cum = 0;
    int b = 0;
    for (; b < NB; ++b) {
        if (cum + h[b] >= (unsigned)kp) break;
        cum += h[b];
    }
    bstar[row] = b;
    rneedA[row] = kp - (int)cum;
}

// ---------------------------------------------------------------------------
// pass 2: same GEMM (bit-identical), sum exp(acos*10) for bins < bstar,
// append boundary-bin values to per-row global lists.
// ---------------------------------------------------------------------------
__global__ __launch_bounds__(512, 2) void kpass2(const short8v* __restrict__ ancT8,
                                                 const char* __restrict__ negTc,
                                                 const int* __restrict__ phoneT,
                                                 const int* __restrict__ phoneA,
                                                 const int* __restrict__ bstar,
                                                 float* __restrict__ partials,
                                                 float* __restrict__ list,
                                                 int* __restrict__ cnt) {
    __shared__ short8v bufB[2][2048];
    __shared__ int phS[SLICE];
    __shared__ float rowpart[BROWS];
    const int tid = threadIdx.x;
    const int w = tid >> 6;
    const int lane = tid & 63;
    const int g = lane >> 4;
    const int c = lane & 15;
    const int rt = blockIdx.x >> 5;
    const int ct = blockIdx.x & 31;
    const int row0 = rt * BROWS;
    const int colbase = ct * SLICE;

    {
        const char* gsrc = negTc + (size_t)colbase * 512;
#pragma unroll
        for (int i = 0; i < 4; ++i)
            gload16(gsrc + i * 8192 + tid * 16, (char*)&bufB[0][0] + i * 8192 + tid * 16);
    }
    if (tid < SLICE / 4)
        *reinterpret_cast<int4*>(&phS[tid * 4]) =
            *reinterpret_cast<const int4*>(phoneT + colbase + tid * 4);

    short8v af[2][8];
#pragma unroll
    for (int mt = 0; mt < 2; ++mt) {
        const int tile = rt * 16 + w * 2 + mt;
#pragma unroll
        for (int ks = 0; ks < 8; ++ks)
            af[mt][ks] = ancT8[(tile * 8 + ks) * 64 + lane];
    }
    // packed per-row scalars: phone (low16) | bstar<<16
    int pb_r[2][4];
#pragma unroll
    for (int mt = 0; mt < 2; ++mt)
#pragma unroll
        for (int j = 0; j < 4; ++j) {
            const int gr = row0 + w * 32 + mt * 16 + g * 4 + j;
            pb_r[mt][j] = (phoneA[gr] & 0xffff) | (bstar[gr] << 16);
        }

    float lsum[2][4];
#pragma unroll
    for (int mt = 0; mt < 2; ++mt)
#pragma unroll
        for (int j = 0; j < 4; ++j) lsum[mt][j] = 0.f;
    __syncthreads();

    for (int t = 0; t < NCHUNK; ++t) {
        const int cur = t & 1;
        if (t < NCHUNK - 1) {
            const char* gsrc = negTc + (size_t)(colbase + (t + 1) * 64) * 512;
#pragma unroll
            for (int i = 0; i < 4; ++i)
                gload16(gsrc + i * 8192 + tid * 16,
                        (char*)&bufB[cur ^ 1][0] + i * 8192 + tid * 16);
        }
        float4v acc[2][4];
#pragma unroll
        for (int mt = 0; mt < 2; ++mt)
#pragma unroll
            for (int nt = 0; nt < 4; ++nt)
                acc[mt][nt] = (float4v){0.f, 0.f, 0.f, 0.f};
        __builtin_amdgcn_s_setprio(1);
#pragma unroll
        for (int nt = 0; nt < 4; ++nt) {
#pragma unroll
            for (int ks = 0; ks < 8; ++ks) {
                short8v bf = bufB[cur][(nt * 8 + ks) * 64 + lane];
                acc[0][nt] = __builtin_amdgcn_mfma_f32_16x16x32_bf16(af[0][ks], bf, acc[0][nt], 0, 0, 0);
                acc[1][nt] = __builtin_amdgcn_mfma_f32_16x16x32_bf16(af[1][ks], bf, acc[1][nt], 0, 0, 0);
            }
        }
        __builtin_amdgcn_s_setprio(0);

#pragma unroll
        for (int nt = 0; nt < 4; ++nt) {
            const int ph = phS[t * 64 + nt * 16 + c];
#pragma unroll
            for (int mt = 0; mt < 2; ++mt) {
#pragma unroll
                for (int j = 0; j < 4; ++j) {
                    const int pb = pb_r[mt][j];
                    if (ph != (pb & 0xffff)) {
                        float v = fminf(1.f, fmaxf(-1.f, acc[mt][nt][j]));
                        int bb = (int)((v + 1.0f) * 32.0f);
                        bb = bb > NB - 1 ? NB - 1 : bb;
                        const int bs = pb >> 16;
                        if (bb < bs) {
                            lsum[mt][j] += expf(acosf(v) * 10.0f);
                        } else if (bb == bs) {
                            const int gr = row0 + w * 32 + mt * 16 + g * 4 + j;
                            int idx = atomicAdd(&cnt[gr], 1);
                            if (idx < CAP) list[(size_t)gr * CAP + idx] = v;
                        }
                    }
                }
            }
        }
        __syncthreads();
    }

    // deterministic per-row reduction across the 16 column-lanes (same g)
#pragma unroll
    for (int mt = 0; mt < 2; ++mt) {
#pragma unroll
        for (int j = 0; j < 4; ++j) {
            float s = lsum[mt][j];
            s += __shfl_xor(s, 1, 64);
            s += __shfl_xor(s, 2, 64);
            s += __shfl_xor(s, 4, 64);
            s += __shfl_xor(s, 8, 64);
            if (c == 0) rowpart[w * 32 + mt * 16 + g * 4 + j] = s;
        }
    }
    __syncthreads();
    if (tid < BROWS)
        partials[(size_t)(row0 + tid) * NSLICE + ct] = rowpart[tid];
}

// ---------------------------------------------------------------------------
// final per-row (one wave): sum partials + sub-histogram refine of the
// boundary bin + tiny exact extraction.
// ---------------------------------------------------------------------------
__global__ __launch_bounds__(64) void kfinal(const float* __restrict__ partials,
                                             const float* __restrict__ list,
                                             const int* __restrict__ cnt,
                                             const int* __restrict__ rneedA,
                                             const int* __restrict__ bstarA,
                                             const float* __restrict__ acosP,
                                             float* __restrict__ logits) {
    __shared__ float sl[CAP];
    __shared__ unsigned subh[256];
    __shared__ float l2[128];
    __shared__ int s_sub, s_cb, s_l2c;
    const int row = blockIdx.x;
    const int lane = threadIdx.x;
    int lc = cnt[row];
    if (lc > CAP) lc = CAP;
    int rn = rneedA[row];
    if (rn > lc) rn = lc;

    // deterministic partials sum (fixed tree)
    float dp = (lane < NSLICE) ? partials[(size_t)row * NSLICE + lane] : 0.f;
#pragma unroll
    for (int off = 1; off < 64; off <<= 1) dp += __shfl_xor(dp, off, 64);
    float den = dp;

    for (int i = lane; i < lc; i += 64) sl[i] = list[(size_t)row * CAP + i];
    for (int i = lane; i < 256; i += 64) subh[i] = 0u;
    if (lane == 0) s_l2c = 0;
    __syncthreads();

    if (rn > 0) {
        const float lo = (float)bstarA[row] * 0.03125f - 1.0f;
        for (int i = lane; i < lc; i += 64) {
            int sb = (int)((sl[i] - lo) * 8192.0f);
            sb = sb < 0 ? 0 : (sb > 255 ? 255 : sb);
            atomicAdd(&subh[sb], 1u);
        }
        __syncthreads();
        if (lane == 0) {
            unsigned cum = 0;
            int b = 0;
            for (; b < 256; ++b) {
                if (cum + subh[b] >= (unsigned)rn) break;
                cum += subh[b];
            }
            s_sub = b > 255 ? 255 : b;
            s_cb = (int)cum;
        }
        __syncthreads();
        const int ss = s_sub, cb = s_cb;
        float ls = 0.f;
        for (int i = lane; i < lc; i += 64) {
            float v = sl[i];
            int sb = (int)((v - lo) * 8192.0f);
            sb = sb < 0 ? 0 : (sb > 255 ? 255 : sb);
            if (sb < ss) {
                ls += expf(acosf(fminf(1.f, fmaxf(-1.f, v))) * 10.0f);
            } else if (sb == ss) {
                int k = atomicAdd(&s_l2c, 1);
                if (k < 128) l2[k] = v;
            }
        }
#pragma unroll
        for (int off = 1; off < 64; off <<= 1) ls += __shfl_xor(ls, off, 64);
        den += ls;
        __syncthreads();

        int rem = rn - cb;
        int n2 = s_l2c < 128 ? s_l2c : 128;
        if (rem > n2) rem = n2;
        // each lane owns up to 2 candidates in registers
        float v0 = lane < n2 ? l2[lane] : 1e30f;
        float v1 = lane + 64 < n2 ? l2[lane + 64] : 1e30f;
        for (int it = 0; it < rem; ++it) {
            float mv = fminf(v0, v1);
            int mi = (v1 < v0) ? lane + 64 : lane;
#pragma unroll
            for (int off = 1; off < 64; off <<= 1) {
                float ov = __shfl_xor(mv, off, 64);
                int oi = __shfl_xor(mi, off, 64);
                if (ov < mv || (ov == mv && oi < mi)) { mv = ov; mi = oi; }
            }
            den += expf(acosf(fminf(1.f, fmaxf(-1.f, mv))) * 10.0f);
            if (mi == lane) v0 = 1e30f;
            if (mi == lane + 64) v1 = 1e30f;
        }
    }
    if (lane == 0) logits[row] = acosP[row] - logf(den);
}

__global__ __launch_bounds__(256) void kloss(const float* __restrict__ logits,
                                             float* __restrict__ out) {
    __shared__ float red[256];
    int tid = threadIdx.x;
    float s = 0.f;
    for (int i = tid; i < BN; i += 256) s += logits[i];
    red[tid] = s;
    __syncthreads();
    for (int st = 128; st > 0; st >>= 1) {
        if (tid < st) red[tid] += red[tid + st];
        __syncthreads();
    }
    if (tid == 0) out[0] = -red[0] / (float)BN;
}

extern "C" void kernel_launch(void* const* d_in, const int* in_sizes, int n_in,
                              void* d_out, int out_size, void* d_ws, size_t ws_size,
                              hipStream_t stream) {
    (void)in_sizes; (void)n_in; (void)out_size; (void)ws_size;
    const float* ctx   = (const float*)d_in[0];
    const float* tgt   = (const float*)d_in[1];
    const int*   mask  = (const int*)d_in[2];
    const int*   phone = (const int*)d_in[3];
    float* out = (float*)d_out;

    char* p = (char*)d_ws;
    unsigned short* negT = (unsigned short*)p;            p += (size_t)BT * TD * 2;       // 16 MB
    unsigned short* ancT = (unsigned short*)p;            p += (size_t)BN * TD * 2;       // 1 MB
    float* acosP  = (float*)p;                            p += (size_t)BN * 4;
    int*   phoneA = (int*)p;                              p += (size_t)BN * 4;
    unsigned* hist = (unsigned*)p;                        p += (size_t)BN * NB * 4;       // 512 KB
    int*   bstarA = (int*)p;                              p += (size_t)BN * 4;
    int*   rneedA = (int*)p;                              p += (size_t)BN * 4;
    int*   cntA   = (int*)p;                              p += (size_t)BN * 4;
    float* partials = (float*)p;                          p += (size_t)BN * NSLICE * 4;   // 256 KB
    float* listA  = (float*)p;                            p += (size_t)BN * CAP * 4;      // 6 MB
    float* logits = (float*)p;                            p += (size_t)BN * 4;

    kzero<<<(BN * NB) / 256, 256, 0, stream>>>(hist, cntA);
    kprep<<<BT / 4, 256, 0, stream>>>(tgt, negT);
    kanchor<<<BN, 64, 0, stream>>>(ctx, tgt, mask, phone, ancT, acosP, phoneA);
    kpass1<<<8 * NSLICE, 512, 0, stream>>>((const short8v*)ancT, (const char*)negT,
                                           phone, phoneA, hist);
    kbstar<<<BN / 256, 256, 0, stream>>>(hist, bstarA, rneedA);
    kpass2<<<8 * NSLICE, 512, 0, stream>>>((const short8v*)ancT, (const char*)negT,
                                           phone, phoneA, bstarA, partials, listA, cntA);
    kfinal<<<BN, 64, 0, stream>>>(partials, listA, cntA, rneedA, bstarA, acosP, logits);
    kloss<<<1, 256, 0, stream>>>(logits, out);
}

// Round 6
// 203.707 us; speedup vs baseline: 1.8111x; 1.4094x over previous
//
#include <hip/hip_runtime.h>
#include <math.h>

#define TT 2048
#define TD 256
#define BN 2048
#define BT 32768
#define KTOP 100
#define CAP 1024     // per-row candidate list capacity
#define THETA -0.15f // candidate threshold on cos
#define BROWS 128    // rows per block (4 waves x 2 tiles x 16)
#define SLICE 512    // cols per block
#define NCHUNK 8     // SLICE / 64
#define FSCALE 301.176470588f  // 256 / 0.85 (kfinal bins over [-1, THETA))

typedef __attribute__((ext_vector_type(8))) short short8v;
typedef __attribute__((ext_vector_type(4))) float float4v;

__device__ __forceinline__ unsigned short f2bf(float f) {
    unsigned u = __float_as_uint(f);
    u += 0x7fffu + ((u >> 16) & 1u);   // round-to-nearest-even
    return (unsigned short)(u >> 16);
}

// ushort offset of (row_or_col, d0 = 4*lane) in the MFMA-fragment-tiled layout
// [blk16][ks(8)][g(4)][c(16)][8 elems]
__device__ __forceinline__ int tile_off_us(int col, int l) {
    int ks = l >> 3;
    int g = (l >> 1) & 3;
    int e = (l & 1) * 4;
    return ((((col >> 4) * 8 + ks) * 4 + g) * 16 + (col & 15)) * 8 + e;
}

__device__ __forceinline__ void gload16(const void* g, void* l) {
    __builtin_amdgcn_global_load_lds(
        (const __attribute__((address_space(1))) unsigned*)g,
        (__attribute__((address_space(3))) unsigned*)l, 16, 0, 0);
}

// ---------------------------------------------------------------------------
__global__ __launch_bounds__(256) void kzero(int* __restrict__ cnt,
                                             int* __restrict__ flag,
                                             unsigned* __restrict__ gh) {
    int i = blockIdx.x * 256 + threadIdx.x;
    if (i < BN) { cnt[i] = 0; flag[i] = 0; }
    if (i < 128) gh[i] = 0u;
}

// global phone histogram (for exact unmasked counts -> kp)
__global__ __launch_bounds__(256) void kghist(const int* __restrict__ phone,
                                              unsigned* __restrict__ gh) {
    __shared__ unsigned h[128];
    const int tid = threadIdx.x;
    if (tid < 128) h[tid] = 0u;
    __syncthreads();
    for (int i = blockIdx.x * 256 + tid; i < BT; i += gridDim.x * 256)
        atomicAdd(&h[phone[i] & 127], 1u);
    __syncthreads();
    if (tid < 128 && h[tid]) atomicAdd(&gh[tid], h[tid]);
}

// normalize negatives -> bf16 fragment-tiled layout. 1 wave per col.
__global__ __launch_bounds__(256) void kprep(const float* __restrict__ tgt,
                                             unsigned short* __restrict__ negT) {
    const int col = blockIdx.x * 4 + (threadIdx.x >> 6);
    const int lane = threadIdx.x & 63;
    float4 v = *reinterpret_cast<const float4*>(tgt + (size_t)col * TD + lane * 4);
    float s = v.x * v.x + v.y * v.y + v.z * v.z + v.w * v.w;
    for (int off = 32; off > 0; off >>= 1) s += __shfl_down(s, off, 64);
    s = __shfl(s, 0, 64);
    const float inv = 1.0f / sqrtf(s);
    ushort4 o;
    o.x = f2bf(v.x * inv); o.y = f2bf(v.y * inv);
    o.z = f2bf(v.z * inv); o.w = f2bf(v.w * inv);
    *reinterpret_cast<ushort4*>(negT + tile_off_us(col, lane)) = o;
}

// per anchor row: normalized anchor (bf16, tiled), acos*10 numerator, phone.
__global__ __launch_bounds__(64) void kanchor(const float* __restrict__ ctx,
                                              const float* __restrict__ tgt,
                                              const int* __restrict__ mask_index,
                                              const int* __restrict__ phone,
                                              unsigned short* __restrict__ ancT,
                                              float* __restrict__ acosP,
                                              int* __restrict__ phoneA) {
    const int r = blockIdx.x;
    const int b = r >> 7;
    const int n = r & 127;
    const int t = mask_index[n];
    const int lane = threadIdx.x;
    const size_t base = ((size_t)b * TT + t) * TD;
    float4 a = *reinterpret_cast<const float4*>(ctx + base + lane * 4);
    float4 p = *reinterpret_cast<const float4*>(tgt + base + lane * 4);
    float sa = a.x * a.x + a.y * a.y + a.z * a.z + a.w * a.w;
    float sp = p.x * p.x + p.y * p.y + p.z * p.z + p.w * p.w;
    float dp = a.x * p.x + a.y * p.y + a.z * p.z + a.w * p.w;
    for (int off = 32; off > 0; off >>= 1) {
        sa += __shfl_down(sa, off, 64);
        sp += __shfl_down(sp, off, 64);
        dp += __shfl_down(dp, off, 64);
    }
    sa = __shfl(sa, 0, 64);
    sp = __shfl(sp, 0, 64);
    dp = __shfl(dp, 0, 64);
    const float an = sqrtf(sa);
    const float inva = 1.0f / an;
    if (lane == 0) {
        float cp = dp / (an * sqrtf(sp));
        cp = fminf(1.f, fmaxf(-1.f, cp));
        acosP[r] = acosf(cp) * 10.0f;
        phoneA[r] = phone[b * TT + t];
    }
    ushort4 o;
    o.x = f2bf(a.x * inva); o.y = f2bf(a.y * inva);
    o.z = f2bf(a.z * inva); o.w = f2bf(a.w * inva);
    *reinterpret_cast<ushort4*>(ancT + tile_off_us(r, lane)) = o;
}

// ---------------------------------------------------------------------------
// single GEMM pass: 128 rows x 512 cols per block, 4 waves, mt=2.
// Double-buffered LDS B chunks; epilogue appends unmasked cos < THETA.
// ---------------------------------------------------------------------------
__global__ __launch_bounds__(256, 2) void kpass(const short8v* __restrict__ ancT8,
                                                const char* __restrict__ negTc,
                                                const int* __restrict__ phoneT,
                                                const int* __restrict__ phoneA,
                                                float* __restrict__ list,
                                                int* __restrict__ cnt) {
    __shared__ short8v bufB[2][2048];   // 2 x 32 KB
    __shared__ int phS[SLICE];
    const int tid = threadIdx.x;
    const int w = tid >> 6;
    const int lane = tid & 63;
    const int g = lane >> 4;
    const int c = lane & 15;
    // bijective XCD swizzle: co-XCD blocks share B slices (ct-major logical)
    const int logical = (blockIdx.x & 7) * 128 + (blockIdx.x >> 3);
    const int ct = logical >> 4;       // 0..63
    const int rt = logical & 15;       // 0..15
    const int row0 = rt * BROWS;
    const int colbase = ct * SLICE;

    {   // stage chunk 0 early
        const char* gsrc = negTc + (size_t)colbase * 512;
#pragma unroll
        for (int i = 0; i < 8; ++i)
            gload16(gsrc + i * 4096 + tid * 16, (char*)&bufB[0][0] + i * 4096 + tid * 16);
    }
    if (tid < SLICE / 4)
        *reinterpret_cast<int4*>(&phS[tid * 4]) =
            *reinterpret_cast<const int4*>(phoneT + colbase + tid * 4);

    short8v af[2][8];
#pragma unroll
    for (int mt = 0; mt < 2; ++mt) {
        const int tile = rt * 8 + w * 2 + mt;
#pragma unroll
        for (int ks = 0; ks < 8; ++ks)
            af[mt][ks] = ancT8[(tile * 8 + ks) * 64 + lane];
    }
    int phA_r[2][4];
#pragma unroll
    for (int mt = 0; mt < 2; ++mt)
#pragma unroll
        for (int j = 0; j < 4; ++j)
            phA_r[mt][j] = phoneA[row0 + w * 32 + mt * 16 + g * 4 + j];
    __syncthreads();   // drains chunk-0 stage

    for (int t = 0; t < NCHUNK; ++t) {
        const int cur = t & 1;
        if (t < NCHUNK - 1) {   // prefetch next chunk into other buffer
            const char* gsrc = negTc + (size_t)(colbase + (t + 1) * 64) * 512;
#pragma unroll
            for (int i = 0; i < 8; ++i)
                gload16(gsrc + i * 4096 + tid * 16,
                        (char*)&bufB[cur ^ 1][0] + i * 4096 + tid * 16);
        }
        float4v acc[2][4];
#pragma unroll
        for (int mt = 0; mt < 2; ++mt)
#pragma unroll
            for (int nt = 0; nt < 4; ++nt)
                acc[mt][nt] = (float4v){0.f, 0.f, 0.f, 0.f};
        __builtin_amdgcn_s_setprio(1);
#pragma unroll
        for (int nt = 0; nt < 4; ++nt) {
#pragma unroll
            for (int ks = 0; ks < 8; ++ks) {
                short8v bf = bufB[cur][(nt * 8 + ks) * 64 + lane];
                acc[0][nt] = __builtin_amdgcn_mfma_f32_16x16x32_bf16(af[0][ks], bf, acc[0][nt], 0, 0, 0);
                acc[1][nt] = __builtin_amdgcn_mfma_f32_16x16x32_bf16(af[1][ks], bf, acc[1][nt], 0, 0, 0);
            }
        }
        __builtin_amdgcn_s_setprio(0);

#pragma unroll
        for (int nt = 0; nt < 4; ++nt) {
            const int ph = phS[t * 64 + nt * 16 + c];
#pragma unroll
            for (int mt = 0; mt < 2; ++mt) {
#pragma unroll
                for (int j = 0; j < 4; ++j) {
                    float v = fminf(1.f, fmaxf(-1.f, acc[mt][nt][j]));
                    if (v < THETA && ph != phA_r[mt][j]) {
                        const int gr = row0 + w * 32 + mt * 16 + g * 4 + j;
                        int idx = atomicAdd(&cnt[gr], 1);
                        if (idx < CAP) list[(size_t)gr * CAP + idx] = v;
                    }
                }
            }
        }
        __syncthreads();   // buffer handoff
    }
}

// ---------------------------------------------------------------------------
// per-row final: exact bottom-kp selection among candidates + exp/acos sum.
// One wave per row. Flags rows needing the exact fallback (never, in practice).
// ---------------------------------------------------------------------------
__global__ __launch_bounds__(64) void kfinal(const float* __restrict__ list,
                                             const int* __restrict__ cnt,
                                             const int* __restrict__ phoneA,
                                             const unsigned* __restrict__ ghist,
                                             const float* __restrict__ acosP,
                                             float* __restrict__ logits,
                                             int* __restrict__ flag) {
    __shared__ float sl[CAP];
    __shared__ unsigned subh[256];
    __shared__ float l2[128];
    __shared__ int s_b, s_cum, s_l2c;
    const int row = blockIdx.x;
    const int lane = threadIdx.x;
    const int un = BT - (int)ghist[phoneA[row] & 127];
    const int kp = un < KTOP ? un : KTOP;
    const int c = cnt[row];
    if (kp <= 0) { if (lane == 0) logits[row] = acosP[row]; return; }
    if (c < kp || c > CAP) { if (lane == 0) flag[row] = 1; return; }

    for (int i = lane; i < c; i += 64) sl[i] = list[(size_t)row * CAP + i];
    for (int i = lane; i < 256; i += 64) subh[i] = 0u;
    if (lane == 0) s_l2c = 0;
    __syncthreads();

    for (int i = lane; i < c; i += 64) {
        int sb = (int)((sl[i] + 1.0f) * FSCALE);
        sb = sb < 0 ? 0 : (sb > 255 ? 255 : sb);
        atomicAdd(&subh[sb], 1u);
    }
    __syncthreads();
    if (lane == 0) {
        unsigned cum = 0;
        int b = 0;
        for (; b < 256; ++b) {
            if (cum + subh[b] >= (unsigned)kp) break;
            cum += subh[b];
        }
        s_b = b > 255 ? 255 : b;
        s_cum = (int)cum;
    }
    __syncthreads();
    const int bs = s_b, cum = s_cum;

    float ls = 0.f;
    for (int i = lane; i < c; i += 64) {
        float v = sl[i];
        int sb = (int)((v + 1.0f) * FSCALE);
        sb = sb < 0 ? 0 : (sb > 255 ? 255 : sb);
        if (sb < bs) {
            ls += expf(acosf(fminf(1.f, fmaxf(-1.f, v))) * 10.0f);
        } else if (sb == bs) {
            int k = atomicAdd(&s_l2c, 1);
            if (k < 128) l2[k] = v;
        }
    }
#pragma unroll
    for (int off = 1; off < 64; off <<= 1) ls += __shfl_xor(ls, off, 64);
    __syncthreads();
    const int n2 = s_l2c;
    if (n2 > 128) { if (lane == 0) flag[row] = 1; return; }

    float den = ls;
    int rem = kp - cum;
    if (rem > n2) rem = n2;   // cannot happen (sum of bins >= kp), safety
    float v0 = lane < n2 ? l2[lane] : 1e30f;
    float v1 = lane + 64 < n2 ? l2[lane + 64] : 1e30f;
    for (int it = 0; it < rem; ++it) {
        float mv = fminf(v0, v1);
        int mi = (v1 < v0) ? lane + 64 : lane;
#pragma unroll
        for (int off = 1; off < 64; off <<= 1) {
            float ov = __shfl_xor(mv, off, 64);
            int oi = __shfl_xor(mi, off, 64);
            if (ov < mv || (ov == mv && oi < mi)) { mv = ov; mi = oi; }
        }
        den += expf(acosf(fminf(1.f, fmaxf(-1.f, mv))) * 10.0f);
        if (mi == lane) v0 = 1e30f;
        if (mi == lane + 64) v1 = 1e30f;
    }
    if (lane == 0) logits[row] = acosP[row] - logf(den);
}

// ---------------------------------------------------------------------------
// exact fallback for flagged rows: recompute the whole row from f32 inputs,
// 2048-bin histogram selection (2x compute, no big LDS). Cold path.
// ---------------------------------------------------------------------------
__global__ __launch_bounds__(256) void kfallback(const float* __restrict__ ctx,
                                                 const float* __restrict__ tgt,
                                                 const int* __restrict__ mask_index,
                                                 const int* __restrict__ phone,
                                                 const int* __restrict__ flag,
                                                 const unsigned* __restrict__ ghist,
                                                 const float* __restrict__ acosP,
                                                 float* __restrict__ logits) {
    const int row = blockIdx.x;
    if (!flag[row]) return;
    __shared__ float anc[TD];
    __shared__ float redf[256];
    __shared__ int redi[256];
    __shared__ unsigned hist[2048];
    __shared__ float lst[512];
    __shared__ int s_b, s_cum, s_lc;
    const int tid = threadIdx.x;
    const int b = row >> 7;
    const int t = mask_index[row & 127];
    const int mp = phone[b * TT + t];

    {   // normalized anchor into LDS
        float x = ctx[((size_t)b * TT + t) * TD + tid];
        redf[tid] = x * x;
        anc[tid] = x;
        __syncthreads();
        for (int s = 128; s > 0; s >>= 1) {
            if (tid < s) redf[tid] += redf[tid + s];
            __syncthreads();
        }
        float inv = 1.0f / sqrtf(redf[0]);
        __syncthreads();
        anc[tid] *= inv;
    }
    for (int i = tid; i < 2048; i += 256) hist[i] = 0u;
    if (tid == 0) s_lc = 0;
    __syncthreads();

    const int un = BT - (int)ghist[mp & 127];
    const int kp = un < KTOP ? un : KTOP;
    if (kp <= 0) { if (tid == 0) logits[row] = acosP[row]; return; }

    // pass 1: histogram
    for (int col = tid; col < BT; col += 256) {
        if (phone[col] == mp) continue;
        const float* nr = tgt + (size_t)col * TD;
        float dot = 0.f, sq = 0.f;
        for (int d = 0; d < TD; d += 4) {
            float4 v = *reinterpret_cast<const float4*>(nr + d);
            dot += anc[d] * v.x + anc[d + 1] * v.y + anc[d + 2] * v.z + anc[d + 3] * v.w;
            sq += v.x * v.x + v.y * v.y + v.z * v.z + v.w * v.w;
        }
        float cv = fminf(1.f, fmaxf(-1.f, dot / sqrtf(sq)));
        int bb = (int)((cv + 1.0f) * 1024.0f);
        bb = bb > 2047 ? 2047 : bb;
        atomicAdd(&hist[bb], 1u);
    }
    __syncthreads();
    if (tid == 0) {
        unsigned cum = 0;
        int bb = 0;
        for (; bb < 2048; ++bb) {
            if (cum + hist[bb] >= (unsigned)kp) break;
            cum += hist[bb];
        }
        s_b = bb > 2047 ? 2047 : bb;
        s_cum = (int)cum;
    }
    __syncthreads();
    const int bs = s_b;

    // pass 2: recompute (bit-identical per col), sum below, collect boundary
    float ls = 0.f;
    for (int col = tid; col < BT; col += 256) {
        if (phone[col] == mp) continue;
        const float* nr = tgt + (size_t)col * TD;
        float dot = 0.f, sq = 0.f;
        for (int d = 0; d < TD; d += 4) {
            float4 v = *reinterpret_cast<const float4*>(nr + d);
            dot += anc[d] * v.x + anc[d + 1] * v.y + anc[d + 2] * v.z + anc[d + 3] * v.w;
            sq += v.x * v.x + v.y * v.y + v.z * v.z + v.w * v.w;
        }
        float cv = fminf(1.f, fmaxf(-1.f, dot / sqrtf(sq)));
        int bb = (int)((cv + 1.0f) * 1024.0f);
        bb = bb > 2047 ? 2047 : bb;
        if (bb < bs) {
            ls += expf(acosf(cv) * 10.0f);
        } else if (bb == bs) {
            int k = atomicAdd(&s_lc, 1);
            if (k < 512) lst[k] = cv;
        }
    }
    redf[tid] = ls;
    __syncthreads();
    for (int s = 128; s > 0; s >>= 1) {
        if (tid < s) redf[tid] += redf[tid + s];
        __syncthreads();
    }
    float den = redf[0];
    __syncthreads();

    int lc = s_lc < 512 ? s_lc : 512;
    int rem = kp - s_cum;
    if (rem > lc) rem = lc;
    for (int it = 0; it < rem; ++it) {
        float mv = 1e30f;
        int mi = -1;
        for (int i = tid; i < lc; i += 256) {
            if (lst[i] < mv) { mv = lst[i]; mi = i; }
        }
        redf[tid] = mv;
        redi[tid] = mi;
        __syncthreads();
        for (int s = 128; s > 0; s >>= 1) {
            if (tid < s && (redf[tid + s] < redf[tid] ||
                            (redf[tid + s] == redf[tid] && redi[tid + s] >= 0 &&
                             (redi[tid] < 0 || redi[tid + s] < redi[tid])))) {
                redf[tid] = redf[tid + s];
                redi[tid] = redi[tid + s];
            }
            __syncthreads();
        }
        if (tid == 0) {
            den += expf(acosf(fminf(1.f, fmaxf(-1.f, redf[0]))) * 10.0f);
            if (redi[0] >= 0) lst[redi[0]] = 1e30f;
            redf[0] = den;
        }
        __syncthreads();
        den = redf[0];
        __syncthreads();
    }
    if (tid == 0) logits[row] = acosP[row] - logf(den);
}

__global__ __launch_bounds__(256) void kloss(const float* __restrict__ logits,
                                             float* __restrict__ out) {
    __shared__ float red[256];
    int tid = threadIdx.x;
    float s = 0.f;
    for (int i = tid; i < BN; i += 256) s += logits[i];
    red[tid] = s;
    __syncthreads();
    for (int st = 128; st > 0; st >>= 1) {
        if (tid < st) red[tid] += red[tid + st];
        __syncthreads();
    }
    if (tid == 0) out[0] = -red[0] / (float)BN;
}

extern "C" void kernel_launch(void* const* d_in, const int* in_sizes, int n_in,
                              void* d_out, int out_size, void* d_ws, size_t ws_size,
                              hipStream_t stream) {
    (void)in_sizes; (void)n_in; (void)out_size; (void)ws_size;
    const float* ctx   = (const float*)d_in[0];
    const float* tgt   = (const float*)d_in[1];
    const int*   mask  = (const int*)d_in[2];
    const int*   phone = (const int*)d_in[3];
    float* out = (float*)d_out;

    char* p = (char*)d_ws;
    unsigned short* negT = (unsigned short*)p;            p += (size_t)BT * TD * 2;   // 16 MB
    unsigned short* ancT = (unsigned short*)p;            p += (size_t)BN * TD * 2;   // 1 MB
    float* acosP  = (float*)p;                            p += (size_t)BN * 4;
    int*   phoneA = (int*)p;                              p += (size_t)BN * 4;
    int*   cntA   = (int*)p;                              p += (size_t)BN * 4;
    int*   flagA  = (int*)p;                              p += (size_t)BN * 4;
    unsigned* ghA = (unsigned*)p;                         p += 128 * 4;
    float* listA  = (float*)p;                            p += (size_t)BN * CAP * 4;  // 8 MB
    float* logits = (float*)p;                            p += (size_t)BN * 4;

    kzero<<<8, 256, 0, stream>>>(cntA, flagA, ghA);
    kghist<<<32, 256, 0, stream>>>(phone, ghA);
    kprep<<<BT / 4, 256, 0, stream>>>(tgt, negT);
    kanchor<<<BN, 64, 0, stream>>>(ctx, tgt, mask, phone, ancT, acosP, phoneA);
    kpass<<<1024, 256, 0, stream>>>((const short8v*)ancT, (const char*)negT,
                                    phone, phoneA, listA, cntA);
    kfinal<<<BN, 64, 0, stream>>>(listA, cntA, phoneA, ghA, acosP, logits, flagA);
    kfallback<<<BN, 256, 0, stream>>>(ctx, tgt, mask, phone, flagA, ghA, acosP, logits);
    kloss<<<1, 256, 0, stream>>>(logits, out);
}

// Round 7
// 202.247 us; speedup vs baseline: 1.8241x; 1.0072x over previous
//
#include <hip/hip_runtime.h>
#include <math.h>

#define TT 2048
#define TD 256
#define BN 2048
#define BT 32768
#define KTOP 100
#define CAP 1024     // per-row candidate list capacity
#define THETA -0.15f // candidate threshold on cos
#define BROWS 128    // rows per block (4 waves x 2 tiles x 16)
#define SLICE 512    // cols per block
#define NCHUNK 8     // SLICE / 64
#define FSCALE 301.176470588f  // 256 / 0.85 (kfinal bins over [-1, THETA))

typedef __attribute__((ext_vector_type(8))) short short8v;
typedef __attribute__((ext_vector_type(4))) float float4v;

__device__ __forceinline__ unsigned short f2bf(float f) {
    unsigned u = __float_as_uint(f);
    u += 0x7fffu + ((u >> 16) & 1u);   // round-to-nearest-even
    return (unsigned short)(u >> 16);
}

// ushort offset of (row_or_col, d0 = 4*lane) in the MFMA-fragment-tiled layout
// [blk16][ks(8)][g(4)][c(16)][8 elems]
__device__ __forceinline__ int tile_off_us(int col, int l) {
    int ks = l >> 3;
    int g = (l >> 1) & 3;
    int e = (l & 1) * 4;
    return ((((col >> 4) * 8 + ks) * 4 + g) * 16 + (col & 15)) * 8 + e;
}

__device__ __forceinline__ void gload16(const void* g, void* l) {
    __builtin_amdgcn_global_load_lds(
        (const __attribute__((address_space(1))) unsigned*)g,
        (__attribute__((address_space(3))) unsigned*)l, 16, 0, 0);
}

// ---------------------------------------------------------------------------
__global__ __launch_bounds__(256) void kzero(int* __restrict__ cnt,
                                             int* __restrict__ flag,
                                             unsigned* __restrict__ gh) {
    int i = blockIdx.x * 256 + threadIdx.x;
    if (i < BN) { cnt[i] = 0; flag[i] = 0; }
    if (i < 128) gh[i] = 0u;
}

// global phone histogram (for exact unmasked counts -> kp)
__global__ __launch_bounds__(256) void kghist(const int* __restrict__ phone,
                                              unsigned* __restrict__ gh) {
    __shared__ unsigned h[128];
    const int tid = threadIdx.x;
    if (tid < 128) h[tid] = 0u;
    __syncthreads();
    for (int i = blockIdx.x * 256 + tid; i < BT; i += gridDim.x * 256)
        atomicAdd(&h[phone[i] & 127], 1u);
    __syncthreads();
    if (tid < 128 && h[tid]) atomicAdd(&gh[tid], h[tid]);
}

// ---------------------------------------------------------------------------
// normalize negatives -> bf16 fragment-tiled layout.
// One block per 16-col tile: LDS transpose, coalesced loads AND stores.
// ---------------------------------------------------------------------------
__global__ __launch_bounds__(256) void kprep(const float* __restrict__ tgt,
                                             unsigned short* __restrict__ negT) {
    __shared__ float tile[16][257];
    __shared__ float psum[16][8];
    __shared__ float inv[16];
    const int tid = threadIdx.x;
    const int cb = blockIdx.x;            // colblk 0..2047

    // load 16 cols x 256 dims, coalesced
    for (int r = 0; r < 16; ++r)
        tile[r][tid] = tgt[((size_t)cb * 16 + r) * TD + tid];
    __syncthreads();
    if (tid < 128) {
        int row = tid >> 3, seg = tid & 7;
        float s = 0.f;
        for (int j = 0; j < 32; ++j) {
            float x = tile[row][seg * 32 + j];
            s += x * x;
        }
        psum[row][seg] = s;
    }
    __syncthreads();
    if (tid < 16) {
        float s = 0.f;
        for (int j = 0; j < 8; ++j) s += psum[tid][j];
        inv[tid] = 1.0f / sqrtf(s);
    }
    __syncthreads();

    // store: entry e = (d0/8)*16 + col holds col's dims [d0, d0+8).
    // thread t writes entries t and t+256 -> two coalesced 16B stores.
    const int col = tid & 15;
    const float iv = inv[col];
    unsigned short* out = negT + (size_t)cb * 4096;   // 8 KB per colblk
#pragma unroll
    for (int half = 0; half < 2; ++half) {
        const int d0 = (tid >> 4) * 8 + half * 128;
        ushort4 o0, o1;
        o0.x = f2bf(tile[col][d0 + 0] * iv);
        o0.y = f2bf(tile[col][d0 + 1] * iv);
        o0.z = f2bf(tile[col][d0 + 2] * iv);
        o0.w = f2bf(tile[col][d0 + 3] * iv);
        o1.x = f2bf(tile[col][d0 + 4] * iv);
        o1.y = f2bf(tile[col][d0 + 5] * iv);
        o1.z = f2bf(tile[col][d0 + 6] * iv);
        o1.w = f2bf(tile[col][d0 + 7] * iv);
        *reinterpret_cast<ushort4*>(out + (size_t)(half * 256 + tid) * 8) = o0;
        *reinterpret_cast<ushort4*>(out + (size_t)(half * 256 + tid) * 8 + 4) = o1;
    }
}

// per anchor row: normalized anchor (bf16, tiled), acos*10 numerator, phone.
__global__ __launch_bounds__(64) void kanchor(const float* __restrict__ ctx,
                                              const float* __restrict__ tgt,
                                              const int* __restrict__ mask_index,
                                              const int* __restrict__ phone,
                                              unsigned short* __restrict__ ancT,
                                              float* __restrict__ acosP,
                                              int* __restrict__ phoneA) {
    const int r = blockIdx.x;
    const int b = r >> 7;
    const int n = r & 127;
    const int t = mask_index[n];
    const int lane = threadIdx.x;
    const size_t base = ((size_t)b * TT + t) * TD;
    float4 a = *reinterpret_cast<const float4*>(ctx + base + lane * 4);
    float4 p = *reinterpret_cast<const float4*>(tgt + base + lane * 4);
    float sa = a.x * a.x + a.y * a.y + a.z * a.z + a.w * a.w;
    float sp = p.x * p.x + p.y * p.y + p.z * p.z + p.w * p.w;
    float dp = a.x * p.x + a.y * p.y + a.z * p.z + a.w * p.w;
    for (int off = 32; off > 0; off >>= 1) {
        sa += __shfl_down(sa, off, 64);
        sp += __shfl_down(sp, off, 64);
        dp += __shfl_down(dp, off, 64);
    }
    sa = __shfl(sa, 0, 64);
    sp = __shfl(sp, 0, 64);
    dp = __shfl(dp, 0, 64);
    const float an = sqrtf(sa);
    const float inva = 1.0f / an;
    if (lane == 0) {
        float cp = dp / (an * sqrtf(sp));
        cp = fminf(1.f, fmaxf(-1.f, cp));
        acosP[r] = acosf(cp) * 10.0f;
        phoneA[r] = phone[b * TT + t];
    }
    ushort4 o;
    o.x = f2bf(a.x * inva); o.y = f2bf(a.y * inva);
    o.z = f2bf(a.z * inva); o.w = f2bf(a.w * inva);
    *reinterpret_cast<ushort4*>(ancT + tile_off_us(r, lane)) = o;
}

// ---------------------------------------------------------------------------
// single GEMM pass: 128 rows x 512 cols per block, 4 waves, mt=2.
// Single 32 KB LDS buffer (3-4 blocks/CU); per chunk:
//   compute -> bar -> issue stage(t+1) -> epilogue(t) overlaps stage -> bar
// ---------------------------------------------------------------------------
__global__ __launch_bounds__(256, 3) void kpass(const short8v* __restrict__ ancT8,
                                                const char* __restrict__ negTc,
                                                const int* __restrict__ phoneT,
                                                const int* __restrict__ phoneA,
                                                float* __restrict__ list,
                                                int* __restrict__ cnt) {
    __shared__ short8v bufB[2048];   // 32 KB, single buffer
    __shared__ int phS[SLICE];
    const int tid = threadIdx.x;
    const int w = tid >> 6;
    const int lane = tid & 63;
    const int g = lane >> 4;
    const int c = lane & 15;
    // bijective XCD swizzle: co-XCD blocks share B slices (ct-major logical)
    const int logical = (blockIdx.x & 7) * 128 + (blockIdx.x >> 3);
    const int ct = logical >> 4;       // 0..63
    const int rt = logical & 15;       // 0..15
    const int row0 = rt * BROWS;
    const int colbase = ct * SLICE;

    {   // stage chunk 0
        const char* gsrc = negTc + (size_t)colbase * 512;
#pragma unroll
        for (int i = 0; i < 8; ++i)
            gload16(gsrc + i * 4096 + tid * 16, (char*)&bufB[0] + i * 4096 + tid * 16);
    }
    if (tid < SLICE / 4)
        *reinterpret_cast<int4*>(&phS[tid * 4]) =
            *reinterpret_cast<const int4*>(phoneT + colbase + tid * 4);

    short8v af[2][8];
#pragma unroll
    for (int mt = 0; mt < 2; ++mt) {
        const int tile = rt * 8 + w * 2 + mt;
#pragma unroll
        for (int ks = 0; ks < 8; ++ks)
            af[mt][ks] = ancT8[(tile * 8 + ks) * 64 + lane];
    }
    int phA_r[2][4];
#pragma unroll
    for (int mt = 0; mt < 2; ++mt)
#pragma unroll
        for (int j = 0; j < 4; ++j)
            phA_r[mt][j] = phoneA[row0 + w * 32 + mt * 16 + g * 4 + j];
    __syncthreads();   // drains chunk-0 stage

    for (int t = 0; t < NCHUNK; ++t) {
        float4v acc[2][4];
#pragma unroll
        for (int mt = 0; mt < 2; ++mt)
#pragma unroll
            for (int nt = 0; nt < 4; ++nt)
                acc[mt][nt] = (float4v){0.f, 0.f, 0.f, 0.f};
        __builtin_amdgcn_s_setprio(1);
#pragma unroll
        for (int nt = 0; nt < 4; ++nt) {
#pragma unroll
            for (int ks = 0; ks < 8; ++ks) {
                short8v bf = bufB[(nt * 8 + ks) * 64 + lane];
                acc[0][nt] = __builtin_amdgcn_mfma_f32_16x16x32_bf16(af[0][ks], bf, acc[0][nt], 0, 0, 0);
                acc[1][nt] = __builtin_amdgcn_mfma_f32_16x16x32_bf16(af[1][ks], bf, acc[1][nt], 0, 0, 0);
            }
        }
        __builtin_amdgcn_s_setprio(0);
        __syncthreads();   // all waves done reading bufB

        if (t < NCHUNK - 1) {   // issue next stage; latency hides under epilogue
            const char* gsrc = negTc + (size_t)(colbase + (t + 1) * 64) * 512;
#pragma unroll
            for (int i = 0; i < 8; ++i)
                gload16(gsrc + i * 4096 + tid * 16,
                        (char*)&bufB[0] + i * 4096 + tid * 16);
        }

#pragma unroll
        for (int nt = 0; nt < 4; ++nt) {
            const int ph = phS[t * 64 + nt * 16 + c];
#pragma unroll
            for (int mt = 0; mt < 2; ++mt) {
#pragma unroll
                for (int j = 0; j < 4; ++j) {
                    float v = fminf(1.f, fmaxf(-1.f, acc[mt][nt][j]));
                    if (v < THETA && ph != phA_r[mt][j]) {
                        const int gr = row0 + w * 32 + mt * 16 + g * 4 + j;
                        int idx = atomicAdd(&cnt[gr], 1);
                        if (idx < CAP) list[(size_t)gr * CAP + idx] = v;
                    }
                }
            }
        }
        __syncthreads();   // drains stage (+ epilogue mem ops)
    }
}

// ---------------------------------------------------------------------------
// per-row final: exact bottom-kp selection among candidates + exp/acos sum.
// One wave per row. Flags rows needing the exact fallback (never, in practice).
// ---------------------------------------------------------------------------
__global__ __launch_bounds__(64) void kfinal(const float* __restrict__ list,
                                             const int* __restrict__ cnt,
                                             const int* __restrict__ phoneA,
                                             const unsigned* __restrict__ ghist,
                                             const float* __restrict__ acosP,
                                             float* __restrict__ logits,
                                             int* __restrict__ flag) {
    __shared__ float sl[CAP];
    __shared__ unsigned subh[256];
    __shared__ float l2[128];
    __shared__ int s_b, s_cum, s_l2c;
    const int row = blockIdx.x;
    const int lane = threadIdx.x;
    const int un = BT - (int)ghist[phoneA[row] & 127];
    const int kp = un < KTOP ? un : KTOP;
    const int c = cnt[row];
    if (kp <= 0) { if (lane == 0) logits[row] = acosP[row]; return; }
    if (c < kp || c > CAP) { if (lane == 0) flag[row] = 1; return; }

    for (int i = lane; i < c; i += 64) sl[i] = list[(size_t)row * CAP + i];
    for (int i = lane; i < 256; i += 64) subh[i] = 0u;
    if (lane == 0) s_l2c = 0;
    __syncthreads();

    for (int i = lane; i < c; i += 64) {
        int sb = (int)((sl[i] + 1.0f) * FSCALE);
        sb = sb < 0 ? 0 : (sb > 255 ? 255 : sb);
        atomicAdd(&subh[sb], 1u);
    }
    __syncthreads();
    if (lane == 0) {
        unsigned cum = 0;
        int b = 0;
        for (; b < 256; ++b) {
            if (cum + subh[b] >= (unsigned)kp) break;
            cum += subh[b];
        }
        s_b = b > 255 ? 255 : b;
        s_cum = (int)cum;
    }
    __syncthreads();
    const int bs = s_b, cum = s_cum;

    float ls = 0.f;
    for (int i = lane; i < c; i += 64) {
        float v = sl[i];
        int sb = (int)((v + 1.0f) * FSCALE);
        sb = sb < 0 ? 0 : (sb > 255 ? 255 : sb);
        if (sb < bs) {
            ls += expf(acosf(fminf(1.f, fmaxf(-1.f, v))) * 10.0f);
        } else if (sb == bs) {
            int k = atomicAdd(&s_l2c, 1);
            if (k < 128) l2[k] = v;
        }
    }
#pragma unroll
    for (int off = 1; off < 64; off <<= 1) ls += __shfl_xor(ls, off, 64);
    __syncthreads();
    const int n2 = s_l2c;
    if (n2 > 128) { if (lane == 0) flag[row] = 1; return; }

    float den = ls;
    int rem = kp - cum;
    if (rem > n2) rem = n2;   // cannot happen (sum of bins >= kp), safety
    float v0 = lane < n2 ? l2[lane] : 1e30f;
    float v1 = lane + 64 < n2 ? l2[lane + 64] : 1e30f;
    for (int it = 0; it < rem; ++it) {
        float mv = fminf(v0, v1);
        int mi = (v1 < v0) ? lane + 64 : lane;
#pragma unroll
        for (int off = 1; off < 64; off <<= 1) {
            float ov = __shfl_xor(mv, off, 64);
            int oi = __shfl_xor(mi, off, 64);
            if (ov < mv || (ov == mv && oi < mi)) { mv = ov; mi = oi; }
        }
        den += expf(acosf(fminf(1.f, fmaxf(-1.f, mv))) * 10.0f);
        if (mi == lane) v0 = 1e30f;
        if (mi == lane + 64) v1 = 1e30f;
    }
    if (lane == 0) logits[row] = acosP[row] - logf(den);
}

// ---------------------------------------------------------------------------
// exact fallback for flagged rows: recompute the whole row from f32 inputs,
// 2048-bin histogram selection (2x compute, no big LDS). Cold path.
// ---------------------------------------------------------------------------
__global__ __launch_bounds__(256) void kfallback(const float* __restrict__ ctx,
                                                 const float* __restrict__ tgt,
                                                 const int* __restrict__ mask_index,
                                                 const int* __restrict__ phone,
                                                 const int* __restrict__ flag,
                                                 const unsigned* __restrict__ ghist,
                                                 const float* __restrict__ acosP,
                                                 float* __restrict__ logits) {
    const int row = blockIdx.x;
    if (!flag[row]) return;
    __shared__ float anc[TD];
    __shared__ float redf[256];
    __shared__ int redi[256];
    __shared__ unsigned hist[2048];
    __shared__ float lst[512];
    __shared__ int s_b, s_cum, s_lc;
    const int tid = threadIdx.x;
    const int b = row >> 7;
    const int t = mask_index[row & 127];
    const int mp = phone[b * TT + t];

    {   // normalized anchor into LDS
        float x = ctx[((size_t)b * TT + t) * TD + tid];
        redf[tid] = x * x;
        anc[tid] = x;
        __syncthreads();
        for (int s = 128; s > 0; s >>= 1) {
            if (tid < s) redf[tid] += redf[tid + s];
            __syncthreads();
        }
        float inv = 1.0f / sqrtf(redf[0]);
        __syncthreads();
        anc[tid] *= inv;
    }
    for (int i = tid; i < 2048; i += 256) hist[i] = 0u;
    if (tid == 0) s_lc = 0;
    __syncthreads();

    const int un = BT - (int)ghist[mp & 127];
    const int kp = un < KTOP ? un : KTOP;
    if (kp <= 0) { if (tid == 0) logits[row] = acosP[row]; return; }

    // pass 1: histogram
    for (int col = tid; col < BT; col += 256) {
        if (phone[col] == mp) continue;
        const float* nr = tgt + (size_t)col * TD;
        float dot = 0.f, sq = 0.f;
        for (int d = 0; d < TD; d += 4) {
            float4 v = *reinterpret_cast<const float4*>(nr + d);
            dot += anc[d] * v.x + anc[d + 1] * v.y + anc[d + 2] * v.z + anc[d + 3] * v.w;
            sq += v.x * v.x + v.y * v.y + v.z * v.z + v.w * v.w;
        }
        float cv = fminf(1.f, fmaxf(-1.f, dot / sqrtf(sq)));
        int bb = (int)((cv + 1.0f) * 1024.0f);
        bb = bb > 2047 ? 2047 : bb;
        atomicAdd(&hist[bb], 1u);
    }
    __syncthreads();
    if (tid == 0) {
        unsigned cum = 0;
        int bb = 0;
        for (; bb < 2048; ++bb) {
            if (cum + hist[bb] >= (unsigned)kp) break;
            cum += hist[bb];
        }
        s_b = bb > 2047 ? 2047 : bb;
        s_cum = (int)cum;
    }
    __syncthreads();
    const int bs = s_b;

    // pass 2: recompute (bit-identical per col), sum below, collect boundary
    float ls = 0.f;
    for (int col = tid; col < BT; col += 256) {
        if (phone[col] == mp) continue;
        const float* nr = tgt + (size_t)col * TD;
        float dot = 0.f, sq = 0.f;
        for (int d = 0; d < TD; d += 4) {
            float4 v = *reinterpret_cast<const float4*>(nr + d);
            dot += anc[d] * v.x + anc[d + 1] * v.y + anc[d + 2] * v.z + anc[d + 3] * v.w;
            sq += v.x * v.x + v.y * v.y + v.z * v.z + v.w * v.w;
        }
        float cv = fminf(1.f, fmaxf(-1.f, dot / sqrtf(sq)));
        int bb = (int)((cv + 1.0f) * 1024.0f);
        bb = bb > 2047 ? 2047 : bb;
        if (bb < bs) {
            ls += expf(acosf(cv) * 10.0f);
        } else if (bb == bs) {
            int k = atomicAdd(&s_lc, 1);
            if (k < 512) lst[k] = cv;
        }
    }
    redf[tid] = ls;
    __syncthreads();
    for (int s = 128; s > 0; s >>= 1) {
        if (tid < s) redf[tid] += redf[tid + s];
        __syncthreads();
    }
    float den = redf[0];
    __syncthreads();

    int lc = s_lc < 512 ? s_lc : 512;
    int rem = kp - s_cum;
    if (rem > lc) rem = lc;
    for (int it = 0; it < rem; ++it) {
        float mv = 1e30f;
        int mi = -1;
        for (int i = tid; i < lc; i += 256) {
            if (lst[i] < mv) { mv = lst[i]; mi = i; }
        }
        redf[tid] = mv;
        redi[tid] = mi;
        __syncthreads();
        for (int s = 128; s > 0; s >>= 1) {
            if (tid < s && (redf[tid + s] < redf[tid] ||
                            (redf[tid + s] == redf[tid] && redi[tid + s] >= 0 &&
                             (redi[tid] < 0 || redi[tid + s] < redi[tid])))) {
                redf[tid] = redf[tid + s];
                redi[tid] = redi[tid + s];
            }
            __syncthreads();
        }
        if (tid == 0) {
            den += expf(acosf(fminf(1.f, fmaxf(-1.f, redf[0]))) * 10.0f);
            if (redi[0] >= 0) lst[redi[0]] = 1e30f;
            redf[0] = den;
        }
        __syncthreads();
        den = redf[0];
        __syncthreads();
    }
    if (tid == 0) logits[row] = acosP[row] - logf(den);
}

__global__ __launch_bounds__(256) void kloss(const float* __restrict__ logits,
                                             float* __restrict__ out) {
    __shared__ float red[256];
    int tid = threadIdx.x;
    float s = 0.f;
    for (int i = tid; i < BN; i += 256) s += logits[i];
    red[tid] = s;
    __syncthreads();
    for (int st = 128; st > 0; st >>= 1) {
        if (tid < st) red[tid] += red[tid + st];
        __syncthreads();
    }
    if (tid == 0) out[0] = -red[0] / (float)BN;
}

extern "C" void kernel_launch(void* const* d_in, const int* in_sizes, int n_in,
                              void* d_out, int out_size, void* d_ws, size_t ws_size,
                              hipStream_t stream) {
    (void)in_sizes; (void)n_in; (void)out_size; (void)ws_size;
    const float* ctx   = (const float*)d_in[0];
    const float* tgt   = (const float*)d_in[1];
    const int*   mask  = (const int*)d_in[2];
    const int*   phone = (const int*)d_in[3];
    float* out = (float*)d_out;

    char* p = (char*)d_ws;
    unsigned short* negT = (unsigned short*)p;            p += (size_t)BT * TD * 2;   // 16 MB
    unsigned short* ancT = (unsigned short*)p;            p += (size_t)BN * TD * 2;   // 1 MB
    float* acosP  = (float*)p;                            p += (size_t)BN * 4;
    int*   phoneA = (int*)p;                              p += (size_t)BN * 4;
    int*   cntA   = (int*)p;                              p += (size_t)BN * 4;
    int*   flagA  = (int*)p;                              p += (size_t)BN * 4;
    unsigned* ghA = (unsigned*)p;                         p += 128 * 4;
    float* listA  = (float*)p;                            p += (size_t)BN * CAP * 4;  // 8 MB
    float* logits = (float*)p;                            p += (size_t)BN * 4;

    kzero<<<8, 256, 0, stream>>>(cntA, flagA, ghA);
    kghist<<<32, 256, 0, stream>>>(phone, ghA);
    kprep<<<BT / 16, 256, 0, stream>>>(tgt, negT);
    kanchor<<<BN, 64, 0, stream>>>(ctx, tgt, mask, phone, ancT, acosP, phoneA);
    kpass<<<1024, 256, 0, stream>>>((const short8v*)ancT, (const char*)negT,
                                    phone, phoneA, listA, cntA);
    kfinal<<<BN, 64, 0, stream>>>(listA, cntA, phoneA, ghA, acosP, logits, flagA);
    kfallback<<<BN, 256, 0, stream>>>(ctx, tgt, mask, phone, flagA, ghA, acosP, logits);
    kloss<<<1, 256, 0, stream>>>(logits, out);
}

// Round 8
// 159.443 us; speedup vs baseline: 2.3138x; 1.2685x over previous
//
#include <hip/hip_runtime.h>
#include <math.h>

#define TT 2048
#define TD 256
#define BN 2048
#define BT 32768
#define KTOP 100
#define CAP 1024     // per-row global candidate list capacity
#define LCAP 1024    // per-block LDS candidate buffer
#define THETA -0.15f // candidate threshold on cos
#define BROWS 128    // rows per block (2x2 waves, Mw=64)
#define SLICE 512    // cols per block
#define NCHUNK 8     // SLICE / 64
#define FSCALE 301.176470588f  // 256 / 0.85 (kfinal bins over [-1, THETA))

typedef __attribute__((ext_vector_type(8))) short short8v;
typedef __attribute__((ext_vector_type(4))) float float4v;

__device__ __forceinline__ unsigned short f2bf(float f) {
    unsigned u = __float_as_uint(f);
    u += 0x7fffu + ((u >> 16) & 1u);   // round-to-nearest-even
    return (unsigned short)(u >> 16);
}

// ushort offset of (row_or_col, d0 = 4*lane) in the MFMA-fragment-tiled layout
// [blk16][ks(8)][g(4)][c(16)][8 elems]
__device__ __forceinline__ int tile_off_us(int col, int l) {
    int ks = l >> 3;
    int g = (l >> 1) & 3;
    int e = (l & 1) * 4;
    return ((((col >> 4) * 8 + ks) * 4 + g) * 16 + (col & 15)) * 8 + e;
}

__device__ __forceinline__ void gload16(const void* g, void* l) {
    __builtin_amdgcn_global_load_lds(
        (const __attribute__((address_space(1))) unsigned*)g,
        (__attribute__((address_space(3))) unsigned*)l, 16, 0, 0);
}

// ---------------------------------------------------------------------------
__global__ __launch_bounds__(256) void kzero(int* __restrict__ cnt,
                                             int* __restrict__ flag,
                                             unsigned* __restrict__ gh) {
    int i = blockIdx.x * 256 + threadIdx.x;
    if (i < BN) { cnt[i] = 0; flag[i] = 0; }
    if (i < 128) gh[i] = 0u;
}

// global phone histogram (for exact unmasked counts -> kp)
__global__ __launch_bounds__(256) void kghist(const int* __restrict__ phone,
                                              unsigned* __restrict__ gh) {
    __shared__ unsigned h[128];
    const int tid = threadIdx.x;
    if (tid < 128) h[tid] = 0u;
    __syncthreads();
    for (int i = blockIdx.x * 256 + tid; i < BT; i += gridDim.x * 256)
        atomicAdd(&h[phone[i] & 127], 1u);
    __syncthreads();
    if (tid < 128 && h[tid]) atomicAdd(&gh[tid], h[tid]);
}

// ---------------------------------------------------------------------------
// normalize negatives -> bf16 fragment-tiled layout.
// One block per 16-col tile: LDS transpose, coalesced loads AND stores.
// ---------------------------------------------------------------------------
__global__ __launch_bounds__(256) void kprep(const float* __restrict__ tgt,
                                             unsigned short* __restrict__ negT) {
    __shared__ float tile[16][257];
    __shared__ float psum[16][8];
    __shared__ float inv[16];
    const int tid = threadIdx.x;
    const int cb = blockIdx.x;            // colblk 0..2047

    for (int r = 0; r < 16; ++r)
        tile[r][tid] = tgt[((size_t)cb * 16 + r) * TD + tid];
    __syncthreads();
    if (tid < 128) {
        int row = tid >> 3, seg = tid & 7;
        float s = 0.f;
        for (int j = 0; j < 32; ++j) {
            float x = tile[row][seg * 32 + j];
            s += x * x;
        }
        psum[row][seg] = s;
    }
    __syncthreads();
    if (tid < 16) {
        float s = 0.f;
        for (int j = 0; j < 8; ++j) s += psum[tid][j];
        inv[tid] = 1.0f / sqrtf(s);
    }
    __syncthreads();

    const int col = tid & 15;
    const float iv = inv[col];
    unsigned short* out = negT + (size_t)cb * 4096;   // 8 KB per colblk
#pragma unroll
    for (int half = 0; half < 2; ++half) {
        const int d0 = (tid >> 4) * 8 + half * 128;
        ushort4 o0, o1;
        o0.x = f2bf(tile[col][d0 + 0] * iv);
        o0.y = f2bf(tile[col][d0 + 1] * iv);
        o0.z = f2bf(tile[col][d0 + 2] * iv);
        o0.w = f2bf(tile[col][d0 + 3] * iv);
        o1.x = f2bf(tile[col][d0 + 4] * iv);
        o1.y = f2bf(tile[col][d0 + 5] * iv);
        o1.z = f2bf(tile[col][d0 + 6] * iv);
        o1.w = f2bf(tile[col][d0 + 7] * iv);
        *reinterpret_cast<ushort4*>(out + (size_t)(half * 256 + tid) * 8) = o0;
        *reinterpret_cast<ushort4*>(out + (size_t)(half * 256 + tid) * 8 + 4) = o1;
    }
}

// per anchor row: normalized anchor (bf16, tiled), acos*10 numerator, phone.
__global__ __launch_bounds__(64) void kanchor(const float* __restrict__ ctx,
                                              const float* __restrict__ tgt,
                                              const int* __restrict__ mask_index,
                                              const int* __restrict__ phone,
                                              unsigned short* __restrict__ ancT,
                                              float* __restrict__ acosP,
                                              int* __restrict__ phoneA) {
    const int r = blockIdx.x;
    const int b = r >> 7;
    const int n = r & 127;
    const int t = mask_index[n];
    const int lane = threadIdx.x;
    const size_t base = ((size_t)b * TT + t) * TD;
    float4 a = *reinterpret_cast<const float4*>(ctx + base + lane * 4);
    float4 p = *reinterpret_cast<const float4*>(tgt + base + lane * 4);
    float sa = a.x * a.x + a.y * a.y + a.z * a.z + a.w * a.w;
    float sp = p.x * p.x + p.y * p.y + p.z * p.z + p.w * p.w;
    float dp = a.x * p.x + a.y * p.y + a.z * p.z + a.w * p.w;
    for (int off = 32; off > 0; off >>= 1) {
        sa += __shfl_down(sa, off, 64);
        sp += __shfl_down(sp, off, 64);
        dp += __shfl_down(dp, off, 64);
    }
    sa = __shfl(sa, 0, 64);
    sp = __shfl(sp, 0, 64);
    dp = __shfl(dp, 0, 64);
    const float an = sqrtf(sa);
    const float inva = 1.0f / an;
    if (lane == 0) {
        float cp = dp / (an * sqrtf(sp));
        cp = fminf(1.f, fmaxf(-1.f, cp));
        acosP[r] = acosf(cp) * 10.0f;
        phoneA[r] = phone[b * TT + t];
    }
    ushort4 o;
    o.x = f2bf(a.x * inva); o.y = f2bf(a.y * inva);
    o.z = f2bf(a.z * inva); o.w = f2bf(a.w * inva);
    *reinterpret_cast<ushort4*>(ancT + tile_off_us(r, lane)) = o;
}

// ---------------------------------------------------------------------------
// single GEMM pass, counted-vmcnt pipeline (T3+T4):
// 128 rows x 512 cols per block; 4 waves in a 2x2 grid (Mw=64, Nw=32).
// Double-buffered LDS B chunks, stages 2-deep, vmcnt(8) not 0 in the loop.
// Inner loop is vmem-free: candidates go to an LDS buffer, flushed at end.
// ---------------------------------------------------------------------------
__global__ __launch_bounds__(256, 2) void kpass(const short8v* __restrict__ ancT8,
                                                const char* __restrict__ negTc,
                                                const int* __restrict__ phoneT,
                                                const int* __restrict__ phoneA,
                                                float* __restrict__ list,
                                                int* __restrict__ cnt,
                                                int* __restrict__ flag) {
    __shared__ short8v bufB[2][2048];   // 2 x 32 KB
    __shared__ int phS[SLICE];          // 2 KB
    __shared__ float candV[LCAP];       // 4 KB
    __shared__ int candR[LCAP];         // 4 KB
    __shared__ int s_nc;
    const int tid = threadIdx.x;
    const int w = tid >> 6;
    const int lane = tid & 63;
    const int g = lane >> 4;
    const int c = lane & 15;
    const int wr = w >> 1;              // row half (0..1)
    const int wc = w & 1;               // col half (0..1)
    // bijective XCD swizzle (1024 % 8 == 0): co-XCD blocks share ct slices
    const int logical = (blockIdx.x & 7) * 128 + (blockIdx.x >> 3);
    const int ct = logical >> 4;        // 0..63
    const int rt = logical & 15;        // 0..15
    const int row0 = rt * BROWS;
    const int colbase = ct * SLICE;

    // ---- prologue: A-frags + phones first (oldest vmem), then 2 stages ----
    short8v af[4][8];
#pragma unroll
    for (int mt = 0; mt < 4; ++mt) {
        const int tile = rt * 8 + wr * 4 + mt;
#pragma unroll
        for (int ks = 0; ks < 8; ++ks)
            af[mt][ks] = ancT8[(tile * 8 + ks) * 64 + lane];
    }
    int phA_r[4][4];
#pragma unroll
    for (int mt = 0; mt < 4; ++mt)
#pragma unroll
        for (int j = 0; j < 4; ++j)
            phA_r[mt][j] = phoneA[row0 + wr * 64 + mt * 16 + g * 4 + j];
    if (tid < SLICE / 4)
        *reinterpret_cast<int4*>(&phS[tid * 4]) =
            *reinterpret_cast<const int4*>(phoneT + colbase + tid * 4);
    if (tid == 0) s_nc = 0;
    __builtin_amdgcn_sched_barrier(0);
    {   // stage chunks 0 and 1 (8 gloads each per thread)
#pragma unroll
        for (int s = 0; s < 2; ++s) {
            const char* gsrc = negTc + (size_t)(colbase + s * 64) * 512;
#pragma unroll
            for (int i = 0; i < 8; ++i)
                gload16(gsrc + i * 4096 + tid * 16,
                        (char*)&bufB[s][0] + i * 4096 + tid * 16);
        }
    }
    asm volatile("s_waitcnt lgkmcnt(0)" ::: "memory");   // phS/s_nc visible pre-barrier

    auto chunk = [&](int t, bool last) {
        if (last) asm volatile("s_waitcnt vmcnt(0)" ::: "memory");
        else      asm volatile("s_waitcnt vmcnt(8)" ::: "memory");
        __builtin_amdgcn_sched_barrier(0);
        __builtin_amdgcn_s_barrier();        // chunk t staged for ALL waves
        __builtin_amdgcn_sched_barrier(0);
        const int cur = t & 1;
        const short8v* bp = &bufB[cur][0];
        float4v acc[4][2];
#pragma unroll
        for (int mt = 0; mt < 4; ++mt)
#pragma unroll
            for (int nt = 0; nt < 2; ++nt)
                acc[mt][nt] = (float4v){0.f, 0.f, 0.f, 0.f};
        __builtin_amdgcn_s_setprio(1);
#pragma unroll
        for (int nt = 0; nt < 2; ++nt) {
            const int cblk = wc * 2 + nt;
#pragma unroll
            for (int ks = 0; ks < 8; ++ks) {
                short8v bf = bp[(cblk * 8 + ks) * 64 + lane];
                acc[0][nt] = __builtin_amdgcn_mfma_f32_16x16x32_bf16(af[0][ks], bf, acc[0][nt], 0, 0, 0);
                acc[1][nt] = __builtin_amdgcn_mfma_f32_16x16x32_bf16(af[1][ks], bf, acc[1][nt], 0, 0, 0);
                acc[2][nt] = __builtin_amdgcn_mfma_f32_16x16x32_bf16(af[2][ks], bf, acc[2][nt], 0, 0, 0);
                acc[3][nt] = __builtin_amdgcn_mfma_f32_16x16x32_bf16(af[3][ks], bf, acc[3][nt], 0, 0, 0);
            }
        }
        __builtin_amdgcn_s_setprio(0);
        __builtin_amdgcn_sched_barrier(0);
        __builtin_amdgcn_s_barrier();        // all waves done reading bufB[cur]
        __builtin_amdgcn_sched_barrier(0);
        if (t + 2 < NCHUNK) {                // refill freed buffer, 2 ahead
            const char* gsrc = negTc + (size_t)(colbase + (t + 2) * 64) * 512;
#pragma unroll
            for (int i = 0; i < 8; ++i)
                gload16(gsrc + i * 4096 + tid * 16,
                        (char*)bp + i * 4096 + tid * 16);
        }
        // vmem-free epilogue: append candidates to LDS
#pragma unroll
        for (int nt = 0; nt < 2; ++nt) {
            const int cblk = wc * 2 + nt;
            const int ph = phS[t * 64 + cblk * 16 + c];
#pragma unroll
            for (int mt = 0; mt < 4; ++mt) {
#pragma unroll
                for (int j = 0; j < 4; ++j) {
                    float v = fminf(1.f, fmaxf(-1.f, acc[mt][nt][j]));
                    if (v < THETA && ph != phA_r[mt][j]) {
                        int k = atomicAdd(&s_nc, 1);
                        if (k < LCAP) {
                            candV[k] = v;
                            candR[k] = row0 + wr * 64 + mt * 16 + g * 4 + j;
                        }
                    }
                }
            }
        }
    };

#pragma unroll 1
    for (int t = 0; t < NCHUNK - 1; ++t) chunk(t, false);
    chunk(NCHUNK - 1, true);

    __syncthreads();
    const int nc = s_nc;
    if (nc > LCAP) {   // astronomically unlikely: flag whole block for fallback
        for (int i = tid; i < BROWS; i += 256) flag[row0 + i] = 1;
    } else {
        for (int i = tid; i < nc; i += 256) {
            const int r = candR[i];
            int idx = atomicAdd(&cnt[r], 1);
            if (idx < CAP) list[(size_t)r * CAP + idx] = candV[i];
        }
    }
}

// ---------------------------------------------------------------------------
// per-row final: exact bottom-kp selection among candidates + exp/acos sum.
// ---------------------------------------------------------------------------
__global__ __launch_bounds__(64) void kfinal(const float* __restrict__ list,
                                             const int* __restrict__ cnt,
                                             const int* __restrict__ phoneA,
                                             const unsigned* __restrict__ ghist,
                                             const float* __restrict__ acosP,
                                             float* __restrict__ logits,
                                             int* __restrict__ flag) {
    __shared__ float sl[CAP];
    __shared__ unsigned subh[256];
    __shared__ float l2[128];
    __shared__ int s_b, s_cum, s_l2c;
    const int row = blockIdx.x;
    const int lane = threadIdx.x;
    const int un = BT - (int)ghist[phoneA[row] & 127];
    const int kp = un < KTOP ? un : KTOP;
    const int c = cnt[row];
    if (kp <= 0) { if (lane == 0) logits[row] = acosP[row]; return; }
    if (c < kp || c > CAP) { if (lane == 0) flag[row] = 1; return; }

    for (int i = lane; i < c; i += 64) sl[i] = list[(size_t)row * CAP + i];
    for (int i = lane; i < 256; i += 64) subh[i] = 0u;
    if (lane == 0) s_l2c = 0;
    __syncthreads();

    for (int i = lane; i < c; i += 64) {
        int sb = (int)((sl[i] + 1.0f) * FSCALE);
        sb = sb < 0 ? 0 : (sb > 255 ? 255 : sb);
        atomicAdd(&subh[sb], 1u);
    }
    __syncthreads();
    if (lane == 0) {
        unsigned cum = 0;
        int b = 0;
        for (; b < 256; ++b) {
            if (cum + subh[b] >= (unsigned)kp) break;
            cum += subh[b];
        }
        s_b = b > 255 ? 255 : b;
        s_cum = (int)cum;
    }
    __syncthreads();
    const int bs = s_b, cum = s_cum;

    float ls = 0.f;
    for (int i = lane; i < c; i += 64) {
        float v = sl[i];
        int sb = (int)((v + 1.0f) * FSCALE);
        sb = sb < 0 ? 0 : (sb > 255 ? 255 : sb);
        if (sb < bs) {
            ls += expf(acosf(fminf(1.f, fmaxf(-1.f, v))) * 10.0f);
        } else if (sb == bs) {
            int k = atomicAdd(&s_l2c, 1);
            if (k < 128) l2[k] = v;
        }
    }
#pragma unroll
    for (int off = 1; off < 64; off <<= 1) ls += __shfl_xor(ls, off, 64);
    __syncthreads();
    const int n2 = s_l2c;
    if (n2 > 128) { if (lane == 0) flag[row] = 1; return; }

    float den = ls;
    int rem = kp - cum;
    if (rem > n2) rem = n2;
    float v0 = lane < n2 ? l2[lane] : 1e30f;
    float v1 = lane + 64 < n2 ? l2[lane + 64] : 1e30f;
    for (int it = 0; it < rem; ++it) {
        float mv = fminf(v0, v1);
        int mi = (v1 < v0) ? lane + 64 : lane;
#pragma unroll
        for (int off = 1; off < 64; off <<= 1) {
            float ov = __shfl_xor(mv, off, 64);
            int oi = __shfl_xor(mi, off, 64);
            if (ov < mv || (ov == mv && oi < mi)) { mv = ov; mi = oi; }
        }
        den += expf(acosf(fminf(1.f, fmaxf(-1.f, mv))) * 10.0f);
        if (mi == lane) v0 = 1e30f;
        if (mi == lane + 64) v1 = 1e30f;
    }
    if (lane == 0) logits[row] = acosP[row] - logf(den);
}

// ---------------------------------------------------------------------------
// exact fallback for flagged rows (cold path, never expected).
// ---------------------------------------------------------------------------
__global__ __launch_bounds__(256) void kfallback(const float* __restrict__ ctx,
                                                 const float* __restrict__ tgt,
                                                 const int* __restrict__ mask_index,
                                                 const int* __restrict__ phone,
                                                 const int* __restrict__ flag,
                                                 const unsigned* __restrict__ ghist,
                                                 const float* __restrict__ acosP,
                                                 float* __restrict__ logits) {
    const int row = blockIdx.x;
    if (!flag[row]) return;
    __shared__ float anc[TD];
    __shared__ float redf[256];
    __shared__ int redi[256];
    __shared__ unsigned hist[2048];
    __shared__ float lst[512];
    __shared__ int s_b, s_cum, s_lc;
    const int tid = threadIdx.x;
    const int b = row >> 7;
    const int t = mask_index[row & 127];
    const int mp = phone[b * TT + t];

    {
        float x = ctx[((size_t)b * TT + t) * TD + tid];
        redf[tid] = x * x;
        anc[tid] = x;
        __syncthreads();
        for (int s = 128; s > 0; s >>= 1) {
            if (tid < s) redf[tid] += redf[tid + s];
            __syncthreads();
        }
        float inv = 1.0f / sqrtf(redf[0]);
        __syncthreads();
        anc[tid] *= inv;
    }
    for (int i = tid; i < 2048; i += 256) hist[i] = 0u;
    if (tid == 0) s_lc = 0;
    __syncthreads();

    const int un = BT - (int)ghist[mp & 127];
    const int kp = un < KTOP ? un : KTOP;
    if (kp <= 0) { if (tid == 0) logits[row] = acosP[row]; return; }

    for (int col = tid; col < BT; col += 256) {
        if (phone[col] == mp) continue;
        const float* nr = tgt + (size_t)col * TD;
        float dot = 0.f, sq = 0.f;
        for (int d = 0; d < TD; d += 4) {
            float4 v = *reinterpret_cast<const float4*>(nr + d);
            dot += anc[d] * v.x + anc[d + 1] * v.y + anc[d + 2] * v.z + anc[d + 3] * v.w;
            sq += v.x * v.x + v.y * v.y + v.z * v.z + v.w * v.w;
        }
        float cv = fminf(1.f, fmaxf(-1.f, dot / sqrtf(sq)));
        int bb = (int)((cv + 1.0f) * 1024.0f);
        bb = bb > 2047 ? 2047 : bb;
        atomicAdd(&hist[bb], 1u);
    }
    __syncthreads();
    if (tid == 0) {
        unsigned cum = 0;
        int bb = 0;
        for (; bb < 2048; ++bb) {
            if (cum + hist[bb] >= (unsigned)kp) break;
            cum += hist[bb];
        }
        s_b = bb > 2047 ? 2047 : bb;
        s_cum = (int)cum;
    }
    __syncthreads();
    const int bs = s_b;

    float ls = 0.f;
    for (int col = tid; col < BT; col += 256) {
        if (phone[col] == mp) continue;
        const float* nr = tgt + (size_t)col * TD;
        float dot = 0.f, sq = 0.f;
        for (int d = 0; d < TD; d += 4) {
            float4 v = *reinterpret_cast<const float4*>(nr + d);
            dot += anc[d] * v.x + anc[d + 1] * v.y + anc[d + 2] * v.z + anc[d + 3] * v.w;
            sq += v.x * v.x + v.y * v.y + v.z * v.z + v.w * v.w;
        }
        float cv = fminf(1.f, fmaxf(-1.f, dot / sqrtf(sq)));
        int bb = (int)((cv + 1.0f) * 1024.0f);
        bb = bb > 2047 ? 2047 : bb;
        if (bb < bs) {
            ls += expf(acosf(cv) * 10.0f);
        } else if (bb == bs) {
            int k = atomicAdd(&s_lc, 1);
            if (k < 512) lst[k] = cv;
        }
    }
    redf[tid] = ls;
    __syncthreads();
    for (int s = 128; s > 0; s >>= 1) {
        if (tid < s) redf[tid] += redf[tid + s];
        __syncthreads();
    }
    float den = redf[0];
    __syncthreads();

    int lc = s_lc < 512 ? s_lc : 512;
    int rem = kp - s_cum;
    if (rem > lc) rem = lc;
    for (int it = 0; it < rem; ++it) {
        float mv = 1e30f;
        int mi = -1;
        for (int i = tid; i < lc; i += 256) {
            if (lst[i] < mv) { mv = lst[i]; mi = i; }
        }
        redf[tid] = mv;
        redi[tid] = mi;
        __syncthreads();
        for (int s = 128; s > 0; s >>= 1) {
            if (tid < s && (redf[tid + s] < redf[tid] ||
                            (redf[tid + s] == redf[tid] && redi[tid + s] >= 0 &&
                             (redi[tid] < 0 || redi[tid + s] < redi[tid])))) {
                redf[tid] = redf[tid + s];
                redi[tid] = redi[tid + s];
            }
            __syncthreads();
        }
        if (tid == 0) {
            den += expf(acosf(fminf(1.f, fmaxf(-1.f, redf[0]))) * 10.0f);
            if (redi[0] >= 0) lst[redi[0]] = 1e30f;
            redf[0] = den;
        }
        __syncthreads();
        den = redf[0];
        __syncthreads();
    }
    if (tid == 0) logits[row] = acosP[row] - logf(den);
}

__global__ __launch_bounds__(256) void kloss(const float* __restrict__ logits,
                                             float* __restrict__ out) {
    __shared__ float red[256];
    int tid = threadIdx.x;
    float s = 0.f;
    for (int i = tid; i < BN; i += 256) s += logits[i];
    red[tid] = s;
    __syncthreads();
    for (int st = 128; st > 0; st >>= 1) {
        if (tid < st) red[tid] += red[tid + st];
        __syncthreads();
    }
    if (tid == 0) out[0] = -red[0] / (float)BN;
}

extern "C" void kernel_launch(void* const* d_in, const int* in_sizes, int n_in,
                              void* d_out, int out_size, void* d_ws, size_t ws_size,
                              hipStream_t stream) {
    (void)in_sizes; (void)n_in; (void)out_size; (void)ws_size;
    const float* ctx   = (const float*)d_in[0];
    const float* tgt   = (const float*)d_in[1];
    const int*   mask  = (const int*)d_in[2];
    const int*   phone = (const int*)d_in[3];
    float* out = (float*)d_out;

    char* p = (char*)d_ws;
    unsigned short* negT = (unsigned short*)p;            p += (size_t)BT * TD * 2;   // 16 MB
    unsigned short* ancT = (unsigned short*)p;            p += (size_t)BN * TD * 2;   // 1 MB
    float* acosP  = (float*)p;                            p += (size_t)BN * 4;
    int*   phoneA = (int*)p;                              p += (size_t)BN * 4;
    int*   cntA   = (int*)p;                              p += (size_t)BN * 4;
    int*   flagA  = (int*)p;                              p += (size_t)BN * 4;
    unsigned* ghA = (unsigned*)p;                         p += 128 * 4;
    float* listA  = (float*)p;                            p += (size_t)BN * CAP * 4;  // 8 MB
    float* logits = (float*)p;                            p += (size_t)BN * 4;

    kzero<<<8, 256, 0, stream>>>(cntA, flagA, ghA);
    kghist<<<32, 256, 0, stream>>>(phone, ghA);
    kprep<<<BT / 16, 256, 0, stream>>>(tgt, negT);
    kanchor<<<BN, 64, 0, stream>>>(ctx, tgt, mask, phone, ancT, acosP, phoneA);
    kpass<<<1024, 256, 0, stream>>>((const short8v*)ancT, (const char*)negT,
                                    phone, phoneA, listA, cntA, flagA);
    kfinal<<<BN, 64, 0, stream>>>(listA, cntA, phoneA, ghA, acosP, logits, flagA);
    kfallback<<<BN, 256, 0, stream>>>(ctx, tgt, mask, phone, flagA, ghA, acosP, logits);
    kloss<<<1, 256, 0, stream>>>(logits, out);
}

// Round 9
// 132.882 us; speedup vs baseline: 2.7763x; 1.1999x over previous
//
#include <hip/hip_runtime.h>
#include <math.h>

#define TT 2048
#define TD 256
#define BN 2048
#define BT 32768
#define KTOP 100
#define CAP 1024     // per-row global candidate list capacity
#define LCAP 1024    // per-block LDS candidate buffer
#define THETA -0.15f // candidate threshold on cos
#define BROWS 128    // rows per block (4 row-groups x Mw=32)
#define SLICE 512    // cols per block
#define NITER 16     // SLICE / 32 (32 cols per iter: 2 col-groups x 16)
#define FSCALE 301.176470588f  // 256 / 0.85 (kfinal bins over [-1, THETA))
#define GH 32        // ghist partial slices

typedef __attribute__((ext_vector_type(8))) short short8v;
typedef __attribute__((ext_vector_type(4))) float float4v;

__device__ __forceinline__ unsigned short f2bf(float f) {
    unsigned u = __float_as_uint(f);
    u += 0x7fffu + ((u >> 16) & 1u);   // round-to-nearest-even
    return (unsigned short)(u >> 16);
}

// ushort offset of (row_or_col, d0 = 4*lane) in the MFMA-fragment-tiled layout
// [blk16][ks(8)][g(4)][c(16)][8 elems]
__device__ __forceinline__ int tile_off_us(int col, int l) {
    int ks = l >> 3;
    int g = (l >> 1) & 3;
    int e = (l & 1) * 4;
    return ((((col >> 4) * 8 + ks) * 4 + g) * 16 + (col & 15)) * 8 + e;
}

// ---------------------------------------------------------------------------
// Fused init kernel. Block ranges:
//   [0, 2048)      : kprep — normalize 16 negatives, store fragment-tiled
//   [2048, 2560)   : kanchor — 4 anchor rows per block
//   [2560, 2592)   : ghist partial — slice (bid-2560) of phones -> ghp
//   [2592, 2600)   : zero cnt/flag
// ---------------------------------------------------------------------------
__global__ __launch_bounds__(256) void kinit(const float* __restrict__ ctx,
                                             const float* __restrict__ tgt,
                                             const int* __restrict__ mask_index,
                                             const int* __restrict__ phone,
                                             unsigned short* __restrict__ negT,
                                             unsigned short* __restrict__ ancT,
                                             float* __restrict__ acosP,
                                             int* __restrict__ phoneA,
                                             unsigned* __restrict__ ghp,
                                             int* __restrict__ cnt,
                                             int* __restrict__ flagA) {
    const int bid = blockIdx.x;
    const int tid = threadIdx.x;

    if (bid < 2048) {   // ---- kprep: colblk bid ----
        __shared__ float tile[16][257];
        __shared__ float psum[16][8];
        __shared__ float inv[16];
        const int cb = bid;
        for (int r = 0; r < 16; ++r)
            tile[r][tid] = tgt[((size_t)cb * 16 + r) * TD + tid];
        __syncthreads();
        if (tid < 128) {
            int row = tid >> 3, seg = tid & 7;
            float s = 0.f;
            for (int j = 0; j < 32; ++j) {
                float x = tile[row][seg * 32 + j];
                s += x * x;
            }
            psum[row][seg] = s;
        }
        __syncthreads();
        if (tid < 16) {
            float s = 0.f;
            for (int j = 0; j < 8; ++j) s += psum[tid][j];
            inv[tid] = 1.0f / sqrtf(s);
        }
        __syncthreads();
        const int col = tid & 15;
        const float iv = inv[col];
        unsigned short* out = negT + (size_t)cb * 4096;
#pragma unroll
        for (int half = 0; half < 2; ++half) {
            const int d0 = (tid >> 4) * 8 + half * 128;
            ushort4 o0, o1;
            o0.x = f2bf(tile[col][d0 + 0] * iv);
            o0.y = f2bf(tile[col][d0 + 1] * iv);
            o0.z = f2bf(tile[col][d0 + 2] * iv);
            o0.w = f2bf(tile[col][d0 + 3] * iv);
            o1.x = f2bf(tile[col][d0 + 4] * iv);
            o1.y = f2bf(tile[col][d0 + 5] * iv);
            o1.z = f2bf(tile[col][d0 + 6] * iv);
            o1.w = f2bf(tile[col][d0 + 7] * iv);
            *reinterpret_cast<ushort4*>(out + (size_t)(half * 256 + tid) * 8) = o0;
            *reinterpret_cast<ushort4*>(out + (size_t)(half * 256 + tid) * 8 + 4) = o1;
        }
        return;
    }
    if (bid < 2560) {   // ---- kanchor: rows (bid-2048)*4 .. +3 ----
        const int r = (bid - 2048) * 4 + (tid >> 6);
        const int lane = tid & 63;
        const int b = r >> 7;
        const int n = r & 127;
        const int t = mask_index[n];
        const size_t base = ((size_t)b * TT + t) * TD;
        float4 a = *reinterpret_cast<const float4*>(ctx + base + lane * 4);
        float4 p = *reinterpret_cast<const float4*>(tgt + base + lane * 4);
        float sa = a.x * a.x + a.y * a.y + a.z * a.z + a.w * a.w;
        float sp = p.x * p.x + p.y * p.y + p.z * p.z + p.w * p.w;
        float dp = a.x * p.x + a.y * p.y + a.z * p.z + a.w * p.w;
        for (int off = 32; off > 0; off >>= 1) {
            sa += __shfl_down(sa, off, 64);
            sp += __shfl_down(sp, off, 64);
            dp += __shfl_down(dp, off, 64);
        }
        sa = __shfl(sa, 0, 64);
        sp = __shfl(sp, 0, 64);
        dp = __shfl(dp, 0, 64);
        const float an = sqrtf(sa);
        const float inva = 1.0f / an;
        if (lane == 0) {
            float cp = dp / (an * sqrtf(sp));
            cp = fminf(1.f, fmaxf(-1.f, cp));
            acosP[r] = acosf(cp) * 10.0f;
            phoneA[r] = phone[b * TT + t];
        }
        ushort4 o;
        o.x = f2bf(a.x * inva); o.y = f2bf(a.y * inva);
        o.z = f2bf(a.z * inva); o.w = f2bf(a.w * inva);
        *reinterpret_cast<ushort4*>(ancT + tile_off_us(r, lane)) = o;
        return;
    }
    if (bid < 2560 + GH) {   // ---- ghist partial slice ----
        __shared__ unsigned h[128];
        const int s = bid - 2560;
        if (tid < 128) h[tid] = 0u;
        __syncthreads();
        const int base = s * (BT / GH);
        for (int i = tid; i < BT / GH; i += 256)
            atomicAdd(&h[phone[base + i] & 127], 1u);
        __syncthreads();
        if (tid < 128) ghp[s * 128 + tid] = h[tid];
        return;
    }
    {   // ---- zero cnt/flag ----
        const int i = (bid - 2592) * 256 + tid;
        if (i < BN) { cnt[i] = 0; flagA[i] = 0; }
    }
}

// ---------------------------------------------------------------------------
// Barrier-free GEMM pass: 128 rows x 512 cols per block, 8 waves
// (4 row-groups x 2 col-groups). B frags read DIRECTLY from L1/L2 into
// registers (fragment-tiled layout -> coalesced 1KB/wave loads). No LDS
// staging, no s_barrier in the hot loop. Candidates -> LDS, flushed once.
// ---------------------------------------------------------------------------
__global__ __launch_bounds__(512, 4) void kpass(const short8v* __restrict__ ancT8,
                                                const short8v* __restrict__ negT8,
                                                const int* __restrict__ phoneT,
                                                const int* __restrict__ phoneA,
                                                float* __restrict__ list,
                                                int* __restrict__ cnt,
                                                int* __restrict__ flag) {
    __shared__ float candV[LCAP];
    __shared__ int candR[LCAP];
    __shared__ int s_nc;
    const int tid = threadIdx.x;
    const int w = tid >> 6;
    const int lane = tid & 63;
    const int g = lane >> 4;
    const int c = lane & 15;
    const int wr = w >> 1;              // row-group 0..3
    const int wc = w & 1;               // col-group 0..1
    // bijective XCD swizzle (1024 % 8 == 0): co-XCD blocks share ct slices
    const int logical = (blockIdx.x & 7) * 128 + (blockIdx.x >> 3);
    const int ct = logical >> 4;        // 0..63
    const int rt = logical & 15;        // 0..15
    const int row0 = rt * BROWS;
    const int colbase = ct * SLICE;

    if (tid == 0) s_nc = 0;

    short8v af[2][8];
#pragma unroll
    for (int mt = 0; mt < 2; ++mt) {
        const int tile = rt * 8 + wr * 2 + mt;
#pragma unroll
        for (int ks = 0; ks < 8; ++ks)
            af[mt][ks] = ancT8[(tile * 8 + ks) * 64 + lane];
    }
    int phA_r[2][4];
#pragma unroll
    for (int mt = 0; mt < 2; ++mt)
#pragma unroll
        for (int j = 0; j < 4; ++j)
            phA_r[mt][j] = phoneA[row0 + wr * 32 + mt * 16 + g * 4 + j];
    __syncthreads();   // s_nc visible

#pragma unroll 2
    for (int it = 0; it < NITER; ++it) {
        const int cb = colbase + it * 32 + wc * 16;   // wave's 16 cols
        const int fb = (cb >> 4) * 8 * 64 + lane;
        short8v bf[8];
#pragma unroll
        for (int ks = 0; ks < 8; ++ks)
            bf[ks] = negT8[fb + ks * 64];
        const int ph = phoneT[cb + c];
        float4v acc0 = (float4v){0.f, 0.f, 0.f, 0.f};
        float4v acc1 = (float4v){0.f, 0.f, 0.f, 0.f};
        __builtin_amdgcn_s_setprio(1);
#pragma unroll
        for (int ks = 0; ks < 8; ++ks) {
            acc0 = __builtin_amdgcn_mfma_f32_16x16x32_bf16(af[0][ks], bf[ks], acc0, 0, 0, 0);
            acc1 = __builtin_amdgcn_mfma_f32_16x16x32_bf16(af[1][ks], bf[ks], acc1, 0, 0, 0);
        }
        __builtin_amdgcn_s_setprio(0);
#pragma unroll
        for (int j = 0; j < 4; ++j) {
            float v0 = fminf(1.f, fmaxf(-1.f, acc0[j]));
            if (v0 < THETA && ph != phA_r[0][j]) {
                int k = atomicAdd(&s_nc, 1);
                if (k < LCAP) {
                    candV[k] = v0;
                    candR[k] = row0 + wr * 32 + g * 4 + j;
                }
            }
            float v1 = fminf(1.f, fmaxf(-1.f, acc1[j]));
            if (v1 < THETA && ph != phA_r[1][j]) {
                int k = atomicAdd(&s_nc, 1);
                if (k < LCAP) {
                    candV[k] = v1;
                    candR[k] = row0 + wr * 32 + 16 + g * 4 + j;
                }
            }
        }
    }

    __syncthreads();
    const int nc = s_nc;
    if (nc > LCAP) {   // astronomically unlikely: flag block rows for fallback
        for (int i = tid; i < BROWS; i += 512) flag[row0 + i] = 1;
    } else {
        for (int i = tid; i < nc; i += 512) {
            const int r = candR[i];
            int idx = atomicAdd(&cnt[r], 1);
            if (idx < CAP) list[(size_t)r * CAP + idx] = candV[i];
        }
    }
}

// ---------------------------------------------------------------------------
// per-row final: exact bottom-kp selection among candidates + exp/acos sum.
// ---------------------------------------------------------------------------
__global__ __launch_bounds__(64) void kfinal(const float* __restrict__ list,
                                             const int* __restrict__ cnt,
                                             const int* __restrict__ phoneA,
                                             const unsigned* __restrict__ ghp,
                                             const float* __restrict__ acosP,
                                             float* __restrict__ logits,
                                             int* __restrict__ flag) {
    __shared__ float sl[CAP];
    __shared__ unsigned subh[256];
    __shared__ float l2[128];
    __shared__ int s_b, s_cum, s_l2c;
    const int row = blockIdx.x;
    const int lane = threadIdx.x;
    const int mp = phoneA[row] & 127;
    int un = BT;
    for (int s = 0; s < GH; ++s) un -= (int)ghp[s * 128 + mp];
    const int kp = un < KTOP ? un : KTOP;
    const int c = cnt[row];
    if (kp <= 0) { if (lane == 0) logits[row] = acosP[row]; return; }
    if (c < kp || c > CAP) { if (lane == 0) flag[row] = 1; return; }

    for (int i = lane; i < c; i += 64) sl[i] = list[(size_t)row * CAP + i];
    for (int i = lane; i < 256; i += 64) subh[i] = 0u;
    if (lane == 0) s_l2c = 0;
    __syncthreads();

    for (int i = lane; i < c; i += 64) {
        int sb = (int)((sl[i] + 1.0f) * FSCALE);
        sb = sb < 0 ? 0 : (sb > 255 ? 255 : sb);
        atomicAdd(&subh[sb], 1u);
    }
    __syncthreads();
    if (lane == 0) {
        unsigned cum = 0;
        int b = 0;
        for (; b < 256; ++b) {
            if (cum + subh[b] >= (unsigned)kp) break;
            cum += subh[b];
        }
        s_b = b > 255 ? 255 : b;
        s_cum = (int)cum;
    }
    __syncthreads();
    const int bs = s_b, cum = s_cum;

    float ls = 0.f;
    for (int i = lane; i < c; i += 64) {
        float v = sl[i];
        int sb = (int)((v + 1.0f) * FSCALE);
        sb = sb < 0 ? 0 : (sb > 255 ? 255 : sb);
        if (sb < bs) {
            ls += expf(acosf(fminf(1.f, fmaxf(-1.f, v))) * 10.0f);
        } else if (sb == bs) {
            int k = atomicAdd(&s_l2c, 1);
            if (k < 128) l2[k] = v;
        }
    }
#pragma unroll
    for (int off = 1; off < 64; off <<= 1) ls += __shfl_xor(ls, off, 64);
    __syncthreads();
    const int n2 = s_l2c;
    if (n2 > 128) { if (lane == 0) flag[row] = 1; return; }

    float den = ls;
    int rem = kp - cum;
    if (rem > n2) rem = n2;
    float v0 = lane < n2 ? l2[lane] : 1e30f;
    float v1 = lane + 64 < n2 ? l2[lane + 64] : 1e30f;
    for (int it = 0; it < rem; ++it) {
        float mv = fminf(v0, v1);
        int mi = (v1 < v0) ? lane + 64 : lane;
#pragma unroll
        for (int off = 1; off < 64; off <<= 1) {
            float ov = __shfl_xor(mv, off, 64);
            int oi = __shfl_xor(mi, off, 64);
            if (ov < mv || (ov == mv && oi < mi)) { mv = ov; mi = oi; }
        }
        den += expf(acosf(fminf(1.f, fmaxf(-1.f, mv))) * 10.0f);
        if (mi == lane) v0 = 1e30f;
        if (mi == lane + 64) v1 = 1e30f;
    }
    if (lane == 0) logits[row] = acosP[row] - logf(den);
}

// ---------------------------------------------------------------------------
// exact fallback for flagged rows (cold path, never expected).
// ---------------------------------------------------------------------------
__global__ __launch_bounds__(256) void kfallback(const float* __restrict__ ctx,
                                                 const float* __restrict__ tgt,
                                                 const int* __restrict__ mask_index,
                                                 const int* __restrict__ phone,
                                                 const int* __restrict__ flag,
                                                 const unsigned* __restrict__ ghp,
                                                 const float* __restrict__ acosP,
                                                 float* __restrict__ logits) {
    const int row = blockIdx.x;
    if (!flag[row]) return;
    __shared__ float anc[TD];
    __shared__ float redf[256];
    __shared__ int redi[256];
    __shared__ unsigned hist[2048];
    __shared__ float lst[512];
    __shared__ int s_b, s_cum, s_lc;
    const int tid = threadIdx.x;
    const int b = row >> 7;
    const int t = mask_index[row & 127];
    const int mp = phone[b * TT + t];

    {
        float x = ctx[((size_t)b * TT + t) * TD + tid];
        redf[tid] = x * x;
        anc[tid] = x;
        __syncthreads();
        for (int s = 128; s > 0; s >>= 1) {
            if (tid < s) redf[tid] += redf[tid + s];
            __syncthreads();
        }
        float inv = 1.0f / sqrtf(redf[0]);
        __syncthreads();
        anc[tid] *= inv;
    }
    for (int i = tid; i < 2048; i += 256) hist[i] = 0u;
    if (tid == 0) s_lc = 0;
    __syncthreads();

    int un = BT;
    for (int s = 0; s < GH; ++s) un -= (int)ghp[s * 128 + (mp & 127)];
    const int kp = un < KTOP ? un : KTOP;
    if (kp <= 0) { if (tid == 0) logits[row] = acosP[row]; return; }

    for (int col = tid; col < BT; col += 256) {
        if (phone[col] == mp) continue;
        const float* nr = tgt + (size_t)col * TD;
        float dot = 0.f, sq = 0.f;
        for (int d = 0; d < TD; d += 4) {
            float4 v = *reinterpret_cast<const float4*>(nr + d);
            dot += anc[d] * v.x + anc[d + 1] * v.y + anc[d + 2] * v.z + anc[d + 3] * v.w;
            sq += v.x * v.x + v.y * v.y + v.z * v.z + v.w * v.w;
        }
        float cv = fminf(1.f, fmaxf(-1.f, dot / sqrtf(sq)));
        int bb = (int)((cv + 1.0f) * 1024.0f);
        bb = bb > 2047 ? 2047 : bb;
        atomicAdd(&hist[bb], 1u);
    }
    __syncthreads();
    if (tid == 0) {
        unsigned cum = 0;
        int bb = 0;
        for (; bb < 2048; ++bb) {
            if (cum + hist[bb] >= (unsigned)kp) break;
            cum += hist[bb];
        }
        s_b = bb > 2047 ? 2047 : bb;
        s_cum = (int)cum;
    }
    __syncthreads();
    const int bs = s_b;

    float ls = 0.f;
    for (int col = tid; col < BT; col += 256) {
        if (phone[col] == mp) continue;
        const float* nr = tgt + (size_t)col * TD;
        float dot = 0.f, sq = 0.f;
        for (int d = 0; d < TD; d += 4) {
            float4 v = *reinterpret_cast<const float4*>(nr + d);
            dot += anc[d] * v.x + anc[d + 1] * v.y + anc[d + 2] * v.z + anc[d + 3] * v.w;
            sq += v.x * v.x + v.y * v.y + v.z * v.z + v.w * v.w;
        }
        float cv = fminf(1.f, fmaxf(-1.f, dot / sqrtf(sq)));
        int bb = (int)((cv + 1.0f) * 1024.0f);
        bb = bb > 2047 ? 2047 : bb;
        if (bb < bs) {
            ls += expf(acosf(cv) * 10.0f);
        } else if (bb == bs) {
            int k = atomicAdd(&s_lc, 1);
            if (k < 512) lst[k] = cv;
        }
    }
    redf[tid] = ls;
    __syncthreads();
    for (int s = 128; s > 0; s >>= 1) {
        if (tid < s) redf[tid] += redf[tid + s];
        __syncthreads();
    }
    float den = redf[0];
    __syncthreads();

    int lc = s_lc < 512 ? s_lc : 512;
    int rem = kp - s_cum;
    if (rem > lc) rem = lc;
    for (int it = 0; it < rem; ++it) {
        float mv = 1e30f;
        int mi = -1;
        for (int i = tid; i < lc; i += 256) {
            if (lst[i] < mv) { mv = lst[i]; mi = i; }
        }
        redf[tid] = mv;
        redi[tid] = mi;
        __syncthreads();
        for (int s = 128; s > 0; s >>= 1) {
            if (tid < s && (redf[tid + s] < redf[tid] ||
                            (redf[tid + s] == redf[tid] && redi[tid + s] >= 0 &&
                             (redi[tid] < 0 || redi[tid + s] < redi[tid])))) {
                redf[tid] = redf[tid + s];
                redi[tid] = redi[tid + s];
            }
            __syncthreads();
        }
        if (tid == 0) {
            den += expf(acosf(fminf(1.f, fmaxf(-1.f, redf[0]))) * 10.0f);
            if (redi[0] >= 0) lst[redi[0]] = 1e30f;
            redf[0] = den;
        }
        __syncthreads();
        den = redf[0];
        __syncthreads();
    }
    if (tid == 0) logits[row] = acosP[row] - logf(den);
}

__global__ __launch_bounds__(256) void kloss(const float* __restrict__ logits,
                                             float* __restrict__ out) {
    __shared__ float red[256];
    int tid = threadIdx.x;
    float s = 0.f;
    for (int i = tid; i < BN; i += 256) s += logits[i];
    red[tid] = s;
    __syncthreads();
    for (int st = 128; st > 0; st >>= 1) {
        if (tid < st) red[tid] += red[tid + st];
        __syncthreads();
    }
    if (tid == 0) out[0] = -red[0] / (float)BN;
}

extern "C" void kernel_launch(void* const* d_in, const int* in_sizes, int n_in,
                              void* d_out, int out_size, void* d_ws, size_t ws_size,
                              hipStream_t stream) {
    (void)in_sizes; (void)n_in; (void)out_size; (void)ws_size;
    const float* ctx   = (const float*)d_in[0];
    const float* tgt   = (const float*)d_in[1];
    const int*   mask  = (const int*)d_in[2];
    const int*   phone = (const int*)d_in[3];
    float* out = (float*)d_out;

    char* p = (char*)d_ws;
    unsigned short* negT = (unsigned short*)p;            p += (size_t)BT * TD * 2;   // 16 MB
    unsigned short* ancT = (unsigned short*)p;            p += (size_t)BN * TD * 2;   // 1 MB
    float* acosP  = (float*)p;                            p += (size_t)BN * 4;
    int*   phoneA = (int*)p;                              p += (size_t)BN * 4;
    int*   cntA   = (int*)p;                              p += (size_t)BN * 4;
    int*   flagA  = (int*)p;                              p += (size_t)BN * 4;
    unsigned* ghp = (unsigned*)p;                         p += (size_t)GH * 128 * 4;
    float* listA  = (float*)p;                            p += (size_t)BN * CAP * 4;  // 8 MB
    float* logits = (float*)p;                            p += (size_t)BN * 4;

    kinit<<<2600, 256, 0, stream>>>(ctx, tgt, mask, phone, negT, ancT,
                                    acosP, phoneA, ghp, cntA, flagA);
    kpass<<<1024, 512, 0, stream>>>((const short8v*)ancT, (const short8v*)negT,
                                    phone, phoneA, listA, cntA, flagA);
    kfinal<<<BN, 64, 0, stream>>>(listA, cntA, phoneA, ghp, acosP, logits, flagA);
    kfallback<<<BN, 256, 0, stream>>>(ctx, tgt, mask, phone, flagA, ghp, acosP, logits);
    kloss<<<1, 256, 0, stream>>>(logits, out);
}